// Round 3
// baseline (120.416 us; speedup 1.0000x reference)
//
#include <hip/hip_runtime.h>

#define HH 16
#define LL 2048
#define DD 64
#define BQ 128
#define BK 64
#define NQ (LL/BQ)   /* 16 */
#define NK (LL/BK)   /* 32 */
#define SCALE 0.125f
#define QSCALE (0.125f * 1.44269504f)   /* fold log2(e): softmax via exp2 */

typedef __attribute__((ext_vector_type(8))) short s8v;   // 8 bf16 (4 VGPR)
typedef __attribute__((ext_vector_type(4))) float f4v;   // 4 fp32 acc

static __device__ __forceinline__ ushort f2bf(float x) {
    unsigned u = __float_as_uint(x);
    u += 0x7fff + ((u >> 16) & 1);       // round-to-nearest-even
    return (ushort)(u >> 16);
}

// ---------------- kernel 1a: per-head k partial sums (128 blocks) ----------------
__global__ void kmean1_kernel(const float* __restrict__ k, float* __restrict__ kpart) {
    int b = blockIdx.x;             // 0..7 token slab of 256
    int h = blockIdx.y;
    int t = threadIdx.x;            // 256
    int d = t & 63, c = t >> 6;
    const float* kh = k + ((size_t)h*LL + (size_t)b*256) * DD;
    float s = 0.f;
    for (int l = c*64; l < c*64 + 64; ++l) s += kh[(size_t)l * DD + d];
    __shared__ float red[4][64];
    red[c][d] = s;
    __syncthreads();
    if (t < 64) kpart[((size_t)h*8 + b)*64 + t] = red[0][t]+red[1][t]+red[2][t]+red[3][t];
}

// ---------------- kernel 1b: reduce partials ----------------
__global__ void kmean2_kernel(const float* __restrict__ kpart, float* __restrict__ kmean) {
    int h = blockIdx.x;
    int t = threadIdx.x;            // 64
    float s = 0.f;
    #pragma unroll
    for (int b = 0; b < 8; ++b) s += kpart[((size_t)h*8 + b)*64 + t];
    kmean[h*DD + t] = s * (1.0f/LL);
}

// ---------------- kernel 2a: q block mean + self-similarity ----------------
__global__ void qstat_kernel(const float* __restrict__ q, const float* __restrict__ simth,
                             float* __restrict__ qm, int* __restrict__ compq) {
    int qi = blockIdx.x, h = blockIdx.y;
    int t = threadIdx.x;            // 128, one token each
    const float* row = q + ((size_t)h*LL + (size_t)qi*BQ + t) * DD;
    float x[DD]; float n2 = 0.f;
    #pragma unroll
    for (int d = 0; d < DD; d += 4) {
        float4 v4 = *(const float4*)(row + d);
        x[d]=v4.x; x[d+1]=v4.y; x[d+2]=v4.z; x[d+3]=v4.w;
        n2 += v4.x*v4.x + v4.y*v4.y + v4.z*v4.z + v4.w*v4.w;
    }
    __shared__ float xs[BQ][DD+1];
    #pragma unroll
    for (int d = 0; d < DD; ++d) xs[t][d] = x[d];
    __syncthreads();
    __shared__ float mean[DD];
    if (t < DD) {
        float s = 0.f;
        for (int r = 0; r < BQ; ++r) s += xs[r][t];
        mean[t] = s * (1.0f/BQ);
    }
    __syncthreads();
    float dot = 0.f, m2 = 0.f;
    #pragma unroll
    for (int d = 0; d < DD; ++d) { dot += x[d]*mean[d]; m2 += mean[d]*mean[d]; }
    float cs = dot / ((sqrtf(n2) + 1e-6f) * (sqrtf(m2) + 1e-6f));
    __shared__ float red[BQ];
    red[t] = cs; __syncthreads();
    for (int sft = BQ/2; sft > 0; sft >>= 1) {
        if (t < sft) red[t] += red[t + sft];
        __syncthreads();
    }
    if (t == 0) compq[h*NQ + qi] = (red[0] * (1.0f/BQ)) > simth[h] ? 1 : 0;
    if (t < DD) qm[((size_t)h*NQ + qi)*DD + t] = mean[t];
}

// ---------------- kernel 2b: k block mean + self-similarity (centered) ----------------
__global__ void kstat_kernel(const float* __restrict__ k, const float* __restrict__ kmean,
                             const float* __restrict__ simth,
                             float* __restrict__ km, int* __restrict__ compk) {
    int ki = blockIdx.x, h = blockIdx.y;
    int t = threadIdx.x;            // 64, one token each
    const float* row = k + ((size_t)h*LL + (size_t)ki*BK + t) * DD;
    const float* mu = kmean + h*DD;
    float x[DD]; float n2 = 0.f;
    #pragma unroll
    for (int d = 0; d < DD; d += 4) {
        float4 v4 = *(const float4*)(row + d);
        v4.x -= mu[d]; v4.y -= mu[d+1]; v4.z -= mu[d+2]; v4.w -= mu[d+3];
        x[d]=v4.x; x[d+1]=v4.y; x[d+2]=v4.z; x[d+3]=v4.w;
        n2 += v4.x*v4.x + v4.y*v4.y + v4.z*v4.z + v4.w*v4.w;
    }
    __shared__ float xs[BK][DD+1];
    #pragma unroll
    for (int d = 0; d < DD; ++d) xs[t][d] = x[d];
    __syncthreads();
    __shared__ float mean[DD];
    {
        float s = 0.f;
        for (int r = 0; r < BK; ++r) s += xs[r][t];
        mean[t] = s * (1.0f/BK);
    }
    __syncthreads();
    float dot = 0.f, m2 = 0.f;
    #pragma unroll
    for (int d = 0; d < DD; ++d) { dot += x[d]*mean[d]; m2 += mean[d]*mean[d]; }
    float cs = dot / ((sqrtf(n2) + 1e-6f) * (sqrtf(m2) + 1e-6f));
    __shared__ float red[BK];
    red[t] = cs; __syncthreads();
    for (int sft = BK/2; sft > 0; sft >>= 1) {
        if (t < sft) red[t] += red[t + sft];
        __syncthreads();
    }
    if (t == 0) compk[h*NK + ki] = (red[0] * (1.0f/BK)) > simth[h] ? 1 : 0;
    km[((size_t)h*NK + ki)*DD + t] = mean[t];
}

// ---------------- kernel 3: block softmax + CDF selection -> packed bitmask ----------------
__global__ void bmask_kernel(const float* __restrict__ qm, const float* __restrict__ km,
                             const int* __restrict__ compq, const int* __restrict__ compk,
                             const float* __restrict__ cdfth, unsigned* __restrict__ bmaskbits) {
    int qi = blockIdx.x, h = blockIdx.y;
    int j = threadIdx.x;            // 32
    __shared__ float ssh[NK];
    __shared__ float p[NK];
    const float* qv = qm + ((size_t)h*NQ + qi)*DD;
    const float* kv = km + ((size_t)h*NK + j)*DD;
    float s = 0.f;
    for (int d = 0; d < DD; ++d) s += qv[d]*kv[d];
    ssh[j] = s * SCALE;
    __syncthreads();
    float m = ssh[0];
    for (int i = 1; i < NK; ++i) m = fmaxf(m, ssh[i]);
    float den = 0.f;
    for (int i = 0; i < NK; ++i) den += expf(ssh[i] - m);
    p[j] = expf(ssh[j] - m) / den;
    __syncthreads();
    float pj = p[j];
    float mass = 0.f;
    for (int i = 0; i < NK; ++i) {
        float pi = p[i];
        if (pi > pj || (pi == pj && i < j)) mass += pi;
    }
    int sel = (mass < cdfth[h]) ? 1 : 0;
    int keep = (sel || !(compq[h*NQ+qi] && compk[h*NK+j])) ? 1 : 0;
    unsigned long long bal = __ballot(keep);
    if (j == 0) bmaskbits[h*NQ + qi] = (unsigned)bal;
}

// ---------------- kernel 3.5: bf16 conversion pre-pass ----------------
// qb = bf16(q * QSCALE), kb = bf16(k - kmean), vTb = bf16(v)^T per head [DD][LL]
__global__ __launch_bounds__(256) void convert_kernel(
        const float* __restrict__ q, const float* __restrict__ k, const float* __restrict__ v,
        const float* __restrict__ kmean,
        ushort* __restrict__ qb, ushort* __restrict__ kb, ushort* __restrict__ vTb) {
    int c = blockIdx.x;   // token chunk of 64 (0..31)
    int h = blockIdx.y;
    int t = threadIdx.x;  // 256
    size_t base = ((size_t)h*LL + (size_t)c*64) * DD;
    const float* mu = kmean + h*DD;
    __shared__ float tile[64][65];
    #pragma unroll
    for (int i = 0; i < 4; ++i) {
        int f = t + i*256;            // float4 index 0..1023
        int d4 = (f & 15) * 4;
        int row = f >> 4;
        float4 qv = ((const float4*)(q + base))[f];
        ushort4 qo;
        qo.x = f2bf(qv.x * QSCALE); qo.y = f2bf(qv.y * QSCALE);
        qo.z = f2bf(qv.z * QSCALE); qo.w = f2bf(qv.w * QSCALE);
        ((ushort4*)(qb + base))[f] = qo;
        float4 kv = ((const float4*)(k + base))[f];
        ushort4 ko;
        ko.x = f2bf(kv.x - mu[d4]);   ko.y = f2bf(kv.y - mu[d4+1]);
        ko.z = f2bf(kv.z - mu[d4+2]); ko.w = f2bf(kv.w - mu[d4+3]);
        ((ushort4*)(kb + base))[f] = ko;
        float4 vv = ((const float4*)(v + base))[f];
        tile[row][d4] = vv.x; tile[row][d4+1] = vv.y;
        tile[row][d4+2] = vv.z; tile[row][d4+3] = vv.w;
    }
    __syncthreads();
    int tok = t & 63;
    int dbase = (t >> 6) * 16;
    #pragma unroll
    for (int i = 0; i < 16; ++i) {
        int d = dbase + i;
        vTb[((size_t)h*DD + d)*LL + (size_t)c*64 + tok] = f2bf(tile[tok][d]);
    }
}

// ---------------- kernel 4: masked flash attention, MFMA bf16 ----------------
// One wave per 16 q-rows. grid = (NQ*8, HH) = 2048 waves -> 2 waves/SIMD.
// Register-double-buffered K/V fragment prefetch (block j+1 in flight during j).
// mfma_f32_16x16x32_bf16 layouts (verified in round 2):
//   A: lane l holds A[l&15][(l>>4)*8 + j]
//   B: lane l holds B[(l>>4)*8 + j][l&15]
//   C/D: lane l, reg r holds D[(l>>4)*4 + r][l&15]
__global__ __launch_bounds__(64, 2) void attn_kernel(
        const ushort* __restrict__ qb, const ushort* __restrict__ kb,
        const ushort* __restrict__ vTb, const unsigned* __restrict__ bmaskbits,
        float* __restrict__ out) {
    int h  = blockIdx.y;
    int qi = blockIdx.x >> 3;
    int w  = blockIdx.x & 7;
    int l  = threadIdx.x;
    int lo = l & 15, hi = l >> 4;
    int r0 = qi*BQ + w*16;

    __shared__ __align__(16) ushort plds[16][80];

    unsigned msk = bmaskbits[h*NQ + qi];

    const ushort* qh = qb  + (size_t)h*LL*DD;
    const ushort* kh = kb  + (size_t)h*LL*DD;
    const ushort* vh = vTb + (size_t)h*DD*LL;

    s8v qa[2];
    #pragma unroll
    for (int kk = 0; kk < 2; ++kk)
        qa[kk] = *(const s8v*)(qh + (size_t)(r0 + lo)*DD + kk*32 + hi*8);

    f4v O[4];
    float mrun[4], lrun[4];
    #pragma unroll
    for (int r = 0; r < 4; ++r) { mrun[r] = -1e30f; lrun[r] = 0.f; }
    #pragma unroll
    for (int nd = 0; nd < 4; ++nd) O[nd] = (f4v){0.f, 0.f, 0.f, 0.f};

    auto nextj = [&]() -> int {
        int j = msk ? (__ffs(msk) - 1) : -1;
        msk &= msk - 1;
        return j;
    };

    auto loadKV = [&](s8v* kf, s8v* vf, int j) {
        const ushort* kbj = kh + (size_t)j*BK*DD;
        const ushort* vbj = vh + (size_t)j*BK;
        #pragma unroll
        for (int ni = 0; ni < 4; ++ni)
            #pragma unroll
            for (int kk = 0; kk < 2; ++kk) {
                kf[ni*2+kk] = *(const s8v*)(kbj + (size_t)(ni*16 + lo)*DD + kk*32 + hi*8);
                vf[ni*2+kk] = *(const s8v*)(vbj + (size_t)(ni*16 + lo)*LL + kk*32 + hi*8);
            }
    };

    auto compute = [&](const s8v* kf, const s8v* vf) {
        f4v S[4];
        #pragma unroll
        for (int ni = 0; ni < 4; ++ni) S[ni] = (f4v){0.f, 0.f, 0.f, 0.f};
        #pragma unroll
        for (int kk = 0; kk < 2; ++kk)
            #pragma unroll
            for (int ni = 0; ni < 4; ++ni)
                S[ni] = __builtin_amdgcn_mfma_f32_16x16x32_bf16(qa[kk], kf[ni*2+kk], S[ni], 0, 0, 0);
        float bm4[4];
        #pragma unroll
        for (int r = 0; r < 4; ++r)
            bm4[r] = fmaxf(fmaxf(S[0][r], S[1][r]), fmaxf(S[2][r], S[3][r]));
        #pragma unroll
        for (int xm = 1; xm <= 8; xm <<= 1)
            #pragma unroll
            for (int r = 0; r < 4; ++r)
                bm4[r] = fmaxf(bm4[r], __shfl_xor(bm4[r], xm));
        bool grow = (bm4[0] > mrun[0]) | (bm4[1] > mrun[1]) |
                    (bm4[2] > mrun[2]) | (bm4[3] > mrun[3]);
        if (__any(grow)) {
            #pragma unroll
            for (int r = 0; r < 4; ++r) {
                float mn = fmaxf(mrun[r], bm4[r]);
                float al = exp2f(mrun[r] - mn);
                mrun[r] = mn;
                lrun[r] *= al;
                #pragma unroll
                for (int nd = 0; nd < 4; ++nd) O[nd][r] *= al;
            }
        }
        #pragma unroll
        for (int ni = 0; ni < 4; ++ni)
            #pragma unroll
            for (int r = 0; r < 4; ++r) {
                float p = exp2f(S[ni][r] - mrun[r]);
                lrun[r] += p;
                plds[hi*4 + r][ni*16 + lo] = f2bf(p);
            }
        #pragma unroll
        for (int kk = 0; kk < 2; ++kk) {
            s8v pa = *(const s8v*)&plds[lo][kk*32 + hi*8];
            #pragma unroll
            for (int nd = 0; nd < 4; ++nd)
                O[nd] = __builtin_amdgcn_mfma_f32_16x16x32_bf16(pa, vf[nd*2+kk], O[nd], 0, 0, 0);
        }
    };

    s8v kfA[8], vfA[8], kfB[8], vfB[8];
    int j = nextj();
    if (j >= 0) {
        loadKV(kfA, vfA, j);
        for (;;) {
            int jn = nextj();
            if (jn >= 0) loadKV(kfB, vfB, jn);
            compute(kfA, vfA);
            if (jn < 0) break;
            int jm = nextj();
            if (jm >= 0) loadKV(kfA, vfA, jm);
            compute(kfB, vfB);
            if (jm < 0) break;
        }
    }

    #pragma unroll
    for (int r = 0; r < 4; ++r) {
        float lsum = lrun[r];
        #pragma unroll
        for (int xm = 1; xm <= 8; xm <<= 1) lsum += __shfl_xor(lsum, xm);
        float inv = 1.0f / lsum;
        int row = r0 + hi*4 + r;
        float* orow = out + ((size_t)h*LL + row)*DD;
        #pragma unroll
        for (int nd = 0; nd < 4; ++nd)
            orow[nd*16 + lo] = O[nd][r] * inv;
    }
}

extern "C" void kernel_launch(void* const* d_in, const int* in_sizes, int n_in,
                              void* d_out, int out_size, void* d_ws, size_t ws_size,
                              hipStream_t stream) {
    const float* q     = (const float*)d_in[0];
    const float* k     = (const float*)d_in[1];
    const float* v     = (const float*)d_in[2];
    const float* simth = (const float*)d_in[3];
    const float* cdfth = (const float*)d_in[4];
    float* out = (float*)d_out;

    float* ws    = (float*)d_ws;
    float* kmean = ws;                       // 16*64
    float* kpart = kmean + HH*DD;            // 16*8*64
    float* qm    = kpart + HH*8*64;          // 16*16*64
    float* km    = qm + HH*NQ*DD;            // 16*32*64
    int*   compq = (int*)(km + HH*NK*DD);    // 256
    int*   compk = compq + HH*NQ;            // 512
    unsigned* bmb = (unsigned*)(compk + HH*NK);  // 256
    size_t off = (size_t)((char*)(bmb + HH*NQ) - (char*)d_ws);
    off = (off + 15) & ~(size_t)15;
    ushort* qbuf = (ushort*)((char*)d_ws + off);
    ushort* kbuf = qbuf + (size_t)HH*LL*DD;
    ushort* vTb  = kbuf + (size_t)HH*LL*DD;

    kmean1_kernel<<<dim3(8, HH), 256, 0, stream>>>(k, kpart);
    kmean2_kernel<<<dim3(HH), 64, 0, stream>>>(kpart, kmean);
    qstat_kernel<<<dim3(NQ, HH), BQ, 0, stream>>>(q, simth, qm, compq);
    kstat_kernel<<<dim3(NK, HH), BK, 0, stream>>>(k, kmean, simth, km, compk);
    convert_kernel<<<dim3(NK, HH), 256, 0, stream>>>(q, k, v, kmean, qbuf, kbuf, vTb);
    bmask_kernel<<<dim3(NQ, HH), NK, 0, stream>>>(qm, km, compq, compk, cdfth, bmb);
    attn_kernel<<<dim3(NQ*8, HH), 64, 0, stream>>>(qbuf, kbuf, vTb, bmb, out);
}

// Round 5
// 97.786 us; speedup vs baseline: 1.2314x; 1.2314x over previous
//
#include <hip/hip_runtime.h>

#define HH 16
#define LL 2048
#define DD 64
#define BQ 128
#define BK 64
#define NQ (LL/BQ)   /* 16 */
#define NK (LL/BK)   /* 32 */
#define SCALE 0.125f
#define QSCALE (0.125f * 1.44269504f)   /* fold log2(e): softmax via exp2 */

typedef __attribute__((ext_vector_type(8))) short s8v;   // 8 bf16 (4 VGPR)
typedef __attribute__((ext_vector_type(4))) float f4v;   // 4 fp32 acc

static __device__ __forceinline__ ushort f2bf(float x) {
    unsigned u = __float_as_uint(x);
    u += 0x7fff + ((u >> 16) & 1);       // round-to-nearest-even
    return (ushort)(u >> 16);
}

// async global->LDS, 16B per lane; LDS dest = uniform base + lane*16
#define GLOAD(src, dst) \
    __builtin_amdgcn_global_load_lds((const __attribute__((address_space(1))) unsigned int*)(src), \
                                     (__attribute__((address_space(3))) unsigned int*)(dst), 16, 0, 0)

// ---------------- kernel 1: per-head k partial sums ----------------
__global__ void kmean1_kernel(const float* __restrict__ k, float* __restrict__ kpart) {
    int b = blockIdx.x;             // 0..7 token slab of 256
    int h = blockIdx.y;
    int t = threadIdx.x;            // 256
    int d = t & 63, c = t >> 6;
    const float* kh = k + ((size_t)h*LL + (size_t)b*256) * DD;
    float s = 0.f;
    for (int l = c*64; l < c*64 + 64; ++l) s += kh[(size_t)l * DD + d];
    __shared__ float red[4][64];
    red[c][d] = s;
    __syncthreads();
    if (t < 64) kpart[((size_t)h*8 + b)*64 + t] = red[0][t]+red[1][t]+red[2][t]+red[3][t];
}

// ---------------- kernel 2a: q block mean + self-similarity ----------------
__global__ void qstat_kernel(const float* __restrict__ q, const float* __restrict__ simth,
                             float* __restrict__ qm, int* __restrict__ compq) {
    int qi = blockIdx.x, h = blockIdx.y;
    int t = threadIdx.x;            // 128, one token each
    const float* row = q + ((size_t)h*LL + (size_t)qi*BQ + t) * DD;
    float x[DD]; float n2 = 0.f;
    #pragma unroll
    for (int d = 0; d < DD; d += 4) {
        float4 v4 = *(const float4*)(row + d);
        x[d]=v4.x; x[d+1]=v4.y; x[d+2]=v4.z; x[d+3]=v4.w;
        n2 += v4.x*v4.x + v4.y*v4.y + v4.z*v4.z + v4.w*v4.w;
    }
    __shared__ float xs[BQ][DD+1];
    #pragma unroll
    for (int d = 0; d < DD; ++d) xs[t][d] = x[d];
    __syncthreads();
    __shared__ float mean[DD];
    if (t < DD) {
        float s = 0.f;
        for (int r = 0; r < BQ; ++r) s += xs[r][t];
        mean[t] = s * (1.0f/BQ);
    }
    __syncthreads();
    float dot = 0.f, m2 = 0.f;
    #pragma unroll
    for (int d = 0; d < DD; ++d) { dot += x[d]*mean[d]; m2 += mean[d]*mean[d]; }
    float cs = dot / ((sqrtf(n2) + 1e-6f) * (sqrtf(m2) + 1e-6f));
    __shared__ float red[BQ];
    red[t] = cs; __syncthreads();
    for (int sft = BQ/2; sft > 0; sft >>= 1) {
        if (t < sft) red[t] += red[t + sft];
        __syncthreads();
    }
    if (t == 0) compq[h*NQ + qi] = (red[0] * (1.0f/BQ)) > simth[h] ? 1 : 0;
    if (t < DD) qm[((size_t)h*NQ + qi)*DD + t] = mean[t];
}

// ---------------- kernel 2b: k block mean + self-similarity (centered) ----------------
__global__ void kstat_kernel(const float* __restrict__ k, const float* __restrict__ kpart,
                             const float* __restrict__ simth,
                             float* __restrict__ km, int* __restrict__ compk) {
    int ki = blockIdx.x, h = blockIdx.y;
    int t = threadIdx.x;            // 64, one token each
    __shared__ float mu_s[DD];
    {
        float s = 0.f;
        #pragma unroll
        for (int b = 0; b < 8; ++b) s += kpart[((size_t)h*8 + b)*64 + t];
        mu_s[t] = s * (1.0f/LL);
    }
    __syncthreads();
    const float* row = k + ((size_t)h*LL + (size_t)ki*BK + t) * DD;
    float x[DD]; float n2 = 0.f;
    #pragma unroll
    for (int d = 0; d < DD; d += 4) {
        float4 v4 = *(const float4*)(row + d);
        v4.x -= mu_s[d]; v4.y -= mu_s[d+1]; v4.z -= mu_s[d+2]; v4.w -= mu_s[d+3];
        x[d]=v4.x; x[d+1]=v4.y; x[d+2]=v4.z; x[d+3]=v4.w;
        n2 += v4.x*v4.x + v4.y*v4.y + v4.z*v4.z + v4.w*v4.w;
    }
    __shared__ float xs[BK][DD+1];
    #pragma unroll
    for (int d = 0; d < DD; ++d) xs[t][d] = x[d];
    __syncthreads();
    __shared__ float mean[DD];
    {
        float s = 0.f;
        for (int r = 0; r < BK; ++r) s += xs[r][t];
        mean[t] = s * (1.0f/BK);
    }
    __syncthreads();
    float dot = 0.f, m2 = 0.f;
    #pragma unroll
    for (int d = 0; d < DD; ++d) { dot += x[d]*mean[d]; m2 += mean[d]*mean[d]; }
    float cs = dot / ((sqrtf(n2) + 1e-6f) * (sqrtf(m2) + 1e-6f));
    __shared__ float red[BK];
    red[t] = cs; __syncthreads();
    for (int sft = BK/2; sft > 0; sft >>= 1) {
        if (t < sft) red[t] += red[t + sft];
        __syncthreads();
    }
    if (t == 0) compk[h*NK + ki] = (red[0] * (1.0f/BK)) > simth[h] ? 1 : 0;
    km[((size_t)h*NK + ki)*DD + t] = mean[t];
}

// ---------------- kernel 3: block softmax + CDF selection -> packed bitmask ----------------
__global__ void bmask_kernel(const float* __restrict__ qm, const float* __restrict__ km,
                             const int* __restrict__ compq, const int* __restrict__ compk,
                             const float* __restrict__ cdfth, unsigned* __restrict__ bmaskbits) {
    int qi = blockIdx.x, h = blockIdx.y;
    int j = threadIdx.x;            // 32
    __shared__ float ssh[NK];
    __shared__ float p[NK];
    const float* qv = qm + ((size_t)h*NQ + qi)*DD;
    const float* kv = km + ((size_t)h*NK + j)*DD;
    float s = 0.f;
    for (int d = 0; d < DD; ++d) s += qv[d]*kv[d];
    ssh[j] = s * SCALE;
    __syncthreads();
    float m = ssh[0];
    for (int i = 1; i < NK; ++i) m = fmaxf(m, ssh[i]);
    float den = 0.f;
    for (int i = 0; i < NK; ++i) den += expf(ssh[i] - m);
    p[j] = expf(ssh[j] - m) / den;
    __syncthreads();
    float pj = p[j];
    float mass = 0.f;
    for (int i = 0; i < NK; ++i) {
        float pi = p[i];
        if (pi > pj || (pi == pj && i < j)) mass += pi;
    }
    int sel = (mass < cdfth[h]) ? 1 : 0;
    int keep = (sel || !(compq[h*NQ+qi] && compk[h*NK+j])) ? 1 : 0;
    unsigned long long bal = __ballot(keep);
    if (j == 0) bmaskbits[h*NQ + qi] = (unsigned)bal;
}

// ---------------- kernel 3.5: bf16 conversion pre-pass ----------------
// qb = bf16(q * QSCALE), kb = bf16(k - kmean), vTb = bf16(v)^T per head [DD][LL]
__global__ __launch_bounds__(256) void convert_kernel(
        const float* __restrict__ q, const float* __restrict__ k, const float* __restrict__ v,
        const float* __restrict__ kpart,
        ushort* __restrict__ qb, ushort* __restrict__ kb, ushort* __restrict__ vTb) {
    int c = blockIdx.x;   // token chunk of 64 (0..31)
    int h = blockIdx.y;
    int t = threadIdx.x;  // 256
    size_t base = ((size_t)h*LL + (size_t)c*64) * DD;
    __shared__ float mu[DD];
    if (t < 64) {
        float s = 0.f;
        #pragma unroll
        for (int b = 0; b < 8; ++b) s += kpart[((size_t)h*8 + b)*64 + t];
        mu[t] = s * (1.0f/LL);
    }
    __syncthreads();
    __shared__ float tile[64][65];
    #pragma unroll
    for (int i = 0; i < 4; ++i) {
        int f = t + i*256;            // float4 index 0..1023
        int d4 = (f & 15) * 4;
        int row = f >> 4;
        float4 qv = ((const float4*)(q + base))[f];
        ushort4 qo;
        qo.x = f2bf(qv.x * QSCALE); qo.y = f2bf(qv.y * QSCALE);
        qo.z = f2bf(qv.z * QSCALE); qo.w = f2bf(qv.w * QSCALE);
        ((ushort4*)(qb + base))[f] = qo;
        float4 kv = ((const float4*)(k + base))[f];
        ushort4 ko;
        ko.x = f2bf(kv.x - mu[d4]);   ko.y = f2bf(kv.y - mu[d4+1]);
        ko.z = f2bf(kv.z - mu[d4+2]); ko.w = f2bf(kv.w - mu[d4+3]);
        ((ushort4*)(kb + base))[f] = ko;
        float4 vv = ((const float4*)(v + base))[f];
        tile[row][d4] = vv.x; tile[row][d4+1] = vv.y;
        tile[row][d4+2] = vv.z; tile[row][d4+3] = vv.w;
    }
    __syncthreads();
    int tok = t & 63;
    int dbase = (t >> 6) * 16;
    #pragma unroll
    for (int i = 0; i < 16; ++i) {
        int d = dbase + i;
        vTb[((size_t)h*DD + d)*LL + (size_t)c*64 + tok] = f2bf(tile[tok][d]);
    }
}

// ---------------- kernel 4: masked flash attention, MFMA bf16, LDS-shared K/V ----------------
// Block = 256 thr (4 waves) per (h, qi, half). Wave w computes q-rows
// [qi*128 + half*64 + w*16, +16). All 4 waves share one double-buffered LDS
// K/V tile staged via global_load_lds with source-swizzled addresses:
// each GLOAD writes 1024B (64 lanes x 16B) = 8 rows of 128B; chunk c lives at
// LDS byte c*1024; LDS[row r][group g] = global[row r][group g^(r&7)], so the
// swizzled ds_read_b128 fragment reads are 2-way-conflict-free.
// msk is uniform per block -> uniform barriers.
__global__ __launch_bounds__(256, 2) void attn_kernel(
        const ushort* __restrict__ qb, const ushort* __restrict__ kb,
        const ushort* __restrict__ vTb, const unsigned* __restrict__ bmaskbits,
        float* __restrict__ out) {
    __shared__ __align__(16) ushort ldsK[2][64*64];   // 2 x 8 KB
    __shared__ __align__(16) ushort ldsV[2][64*64];   // 2 x 8 KB
    __shared__ __align__(16) ushort plds[4][16][72];  // 9 KB, stride 144B (16B-aligned rows)

    int h    = blockIdx.y;
    int qi   = blockIdx.x >> 1;
    int half = blockIdx.x & 1;
    int tid  = threadIdx.x;
    int w    = tid >> 6;
    int l    = tid & 63;
    int lo = l & 15, hi = l >> 4;
    int r0 = qi*BQ + half*64 + w*16;

    unsigned msk = bmaskbits[h*NQ + qi];

    const ushort* qh = qb  + (size_t)h*LL*DD;
    const char*   kh = (const char*)(kb  + (size_t)h*LL*DD);   // block j at +j*8192B
    const char*   vh = (const char*)(vTb + (size_t)h*DD*LL);   // row d at +d*4096B; block j at +j*128B

    // ---- staging source offsets (per lane, bytes) ----
    int srow = l >> 3;                       // row within 8-row chunk
    int sgx  = ((l & 7) ^ srow) * 16;        // source 16B-group (inverse swizzle)
    int c0 = 2*w, c1 = 2*w + 1;              // this wave's chunks
    size_t ks0 = (size_t)(c0*8 + srow)*128 + sgx;
    size_t ks1 = (size_t)(c1*8 + srow)*128 + sgx;
    size_t vs0 = (size_t)(c0*8 + srow)*(LL*2) + sgx;
    size_t vs1 = (size_t)(c1*8 + srow)*(LL*2) + sgx;
    int dst0 = c0*1024, dst1 = c1*1024;      // uniform LDS byte base (HW adds lane*16)

    // ---- fragment read offsets (ushort index) ----
    int p0 = (hi)     ^ (lo & 7);            // kk=0 swizzled group
    int p1 = (4 + hi) ^ (lo & 7);            // kk=1
    int kidx0 = lo*64 + p0*8;
    int kidx1 = lo*64 + p1*8;

    // Q A-frags
    s8v qa[2];
    #pragma unroll
    for (int kk = 0; kk < 2; ++kk)
        qa[kk] = *(const s8v*)(qh + (size_t)(r0 + lo)*DD + kk*32 + hi*8);

    f4v O[4];
    float mrun[4], lrun[4];
    #pragma unroll
    for (int r = 0; r < 4; ++r) { mrun[r] = -1e30f; lrun[r] = 0.f; }
    #pragma unroll
    for (int nd = 0; nd < 4; ++nd) O[nd] = (f4v){0.f, 0.f, 0.f, 0.f};

    auto stage = [&](int buf, int j) {
        const char* kj = kh + (size_t)j*8192;
        const char* vj = vh + (size_t)j*128;
        char* kd = (char*)&ldsK[buf][0];
        char* vd = (char*)&ldsV[buf][0];
        GLOAD(kj + ks0, kd + dst0);
        GLOAD(kj + ks1, kd + dst1);
        GLOAD(vj + vs0, vd + dst0);
        GLOAD(vj + vs1, vd + dst1);
    };

    auto compute = [&](const ushort* Kb, const ushort* Vb) {
        f4v S[4];
        #pragma unroll
        for (int ni = 0; ni < 4; ++ni) S[ni] = (f4v){0.f, 0.f, 0.f, 0.f};
        #pragma unroll
        for (int ni = 0; ni < 4; ++ni) {
            s8v kf0 = *(const s8v*)(Kb + ni*1024 + kidx0);
            s8v kf1 = *(const s8v*)(Kb + ni*1024 + kidx1);
            S[ni] = __builtin_amdgcn_mfma_f32_16x16x32_bf16(qa[0], kf0, S[ni], 0, 0, 0);
            S[ni] = __builtin_amdgcn_mfma_f32_16x16x32_bf16(qa[1], kf1, S[ni], 0, 0, 0);
        }
        float bm4[4];
        #pragma unroll
        for (int r = 0; r < 4; ++r)
            bm4[r] = fmaxf(fmaxf(S[0][r], S[1][r]), fmaxf(S[2][r], S[3][r]));
        #pragma unroll
        for (int xm = 1; xm <= 8; xm <<= 1)
            #pragma unroll
            for (int r = 0; r < 4; ++r)
                bm4[r] = fmaxf(bm4[r], __shfl_xor(bm4[r], xm));
        bool grow = (bm4[0] > mrun[0]) | (bm4[1] > mrun[1]) |
                    (bm4[2] > mrun[2]) | (bm4[3] > mrun[3]);
        if (__any(grow)) {
            #pragma unroll
            for (int r = 0; r < 4; ++r) {
                float mn = fmaxf(mrun[r], bm4[r]);
                float al = __builtin_amdgcn_exp2f(mrun[r] - mn);
                mrun[r] = mn;
                lrun[r] *= al;
                #pragma unroll
                for (int nd = 0; nd < 4; ++nd) O[nd][r] *= al;
            }
        }
        #pragma unroll
        for (int ni = 0; ni < 4; ++ni)
            #pragma unroll
            for (int r = 0; r < 4; ++r) {
                float p = __builtin_amdgcn_exp2f(S[ni][r] - mrun[r]);
                lrun[r] += p;
                plds[w][hi*4 + r][ni*16 + lo] = f2bf(p);
            }
        #pragma unroll
        for (int kk = 0; kk < 2; ++kk) {
            s8v pa = *(const s8v*)&plds[w][lo][kk*32 + hi*8];
            int kidx = kk ? kidx1 : kidx0;
            #pragma unroll
            for (int nd = 0; nd < 4; ++nd) {
                s8v vf = *(const s8v*)(Vb + nd*1024 + kidx);
                O[nd] = __builtin_amdgcn_mfma_f32_16x16x32_bf16(pa, vf, O[nd], 0, 0, 0);
            }
        }
    };

    // ---- 2-phase double-buffered main loop (msk uniform across block) ----
    int j0 = __ffs(msk) - 1; msk &= msk - 1;
    stage(0, j0);
    for (;;) {
        __syncthreads();                      // drains vmcnt: buf0 ready, buf1 free
        int jn = msk ? __ffs(msk) - 1 : -1; msk &= msk - 1;
        if (jn >= 0) stage(1, jn);
        compute(&ldsK[0][0], &ldsV[0][0]);
        if (jn < 0) break;
        __syncthreads();
        int jm = msk ? __ffs(msk) - 1 : -1; msk &= msk - 1;
        if (jm >= 0) stage(0, jm);
        compute(&ldsK[1][0], &ldsV[1][0]);
        if (jm < 0) break;
    }

    // epilogue
    #pragma unroll
    for (int r = 0; r < 4; ++r) {
        float lsum = lrun[r];
        #pragma unroll
        for (int xm = 1; xm <= 8; xm <<= 1) lsum += __shfl_xor(lsum, xm);
        float inv = 1.0f / lsum;
        int row = r0 + hi*4 + r;
        float* orow = out + ((size_t)h*LL + row)*DD;
        #pragma unroll
        for (int nd = 0; nd < 4; ++nd)
            orow[nd*16 + lo] = O[nd][r] * inv;
    }
}

extern "C" void kernel_launch(void* const* d_in, const int* in_sizes, int n_in,
                              void* d_out, int out_size, void* d_ws, size_t ws_size,
                              hipStream_t stream) {
    const float* q     = (const float*)d_in[0];
    const float* k     = (const float*)d_in[1];
    const float* v     = (const float*)d_in[2];
    const float* simth = (const float*)d_in[3];
    const float* cdfth = (const float*)d_in[4];
    float* out = (float*)d_out;

    float* ws    = (float*)d_ws;
    float* kpart = ws;                       // 16*8*64
    float* qm    = kpart + HH*8*64;          // 16*16*64
    float* km    = qm + HH*NQ*DD;            // 16*32*64
    int*   compq = (int*)(km + HH*NK*DD);    // 256
    int*   compk = compq + HH*NQ;            // 512
    unsigned* bmb = (unsigned*)(compk + HH*NK);  // 256
    size_t off = (size_t)((char*)(bmb + HH*NQ) - (char*)d_ws);
    off = (off + 15) & ~(size_t)15;
    ushort* qbuf = (ushort*)((char*)d_ws + off);
    ushort* kbuf = qbuf + (size_t)HH*LL*DD;
    ushort* vTb  = kbuf + (size_t)HH*LL*DD;

    kmean1_kernel<<<dim3(8, HH), 256, 0, stream>>>(k, kpart);
    qstat_kernel<<<dim3(NQ, HH), BQ, 0, stream>>>(q, simth, qm, compq);
    kstat_kernel<<<dim3(NK, HH), BK, 0, stream>>>(k, kpart, simth, km, compk);
    convert_kernel<<<dim3(NK, HH), 256, 0, stream>>>(q, k, v, kpart, qbuf, kbuf, vTb);
    bmask_kernel<<<dim3(NQ, HH), NK, 0, stream>>>(qm, km, compq, compk, cdfth, bmb);
    attn_kernel<<<dim3(NQ*2, HH), 256, 0, stream>>>(qbuf, kbuf, vTb, bmb, out);
}

// Round 6
// 81.806 us; speedup vs baseline: 1.4720x; 1.1953x over previous
//
#include <hip/hip_runtime.h>

#define HH 16
#define LL 2048
#define DD 64
#define BQ 128
#define BK 64
#define NQ (LL/BQ)   /* 16 */
#define NK (LL/BK)   /* 32 */
#define SCALE 0.125f
#define QSCALE (0.125f * 1.44269504f)   /* fold log2(e): softmax via exp2 */

typedef __attribute__((ext_vector_type(8))) short s8v;   // 8 bf16 (4 VGPR)
typedef __attribute__((ext_vector_type(4))) float f4v;   // 4 fp32 acc

static __device__ __forceinline__ ushort f2bf(float x) {
    unsigned u = __float_as_uint(x);
    u += 0x7fff + ((u >> 16) & 1);       // round-to-nearest-even
    return (ushort)(u >> 16);
}

// async global->LDS, 16B per lane; LDS dest = uniform base + lane*16
#define GLOAD(src, dst) \
    __builtin_amdgcn_global_load_lds((const __attribute__((address_space(1))) unsigned int*)(src), \
                                     (__attribute__((address_space(3))) unsigned int*)(dst), 16, 0, 0)

// ---------------- kernel 1: per-head k partial sums ----------------
__global__ void kmean1_kernel(const float* __restrict__ k, float* __restrict__ kpart) {
    int b = blockIdx.x;             // 0..7 token slab of 256
    int h = blockIdx.y;
    int t = threadIdx.x;            // 256
    int d = t & 63, c = t >> 6;
    const float* kh = k + ((size_t)h*LL + (size_t)b*256) * DD;
    float s = 0.f;
    for (int l = c*64; l < c*64 + 64; ++l) s += kh[(size_t)l * DD + d];
    __shared__ float red[4][64];
    red[c][d] = s;
    __syncthreads();
    if (t < 64) kpart[((size_t)h*8 + b)*64 + t] = red[0][t]+red[1][t]+red[2][t]+red[3][t];
}

// ---------------- kernel 2a: q stats + q bf16 convert (fused) ----------------
__global__ void qstat_kernel(const float* __restrict__ q, const float* __restrict__ simth,
                             float* __restrict__ qm, int* __restrict__ compq,
                             ushort* __restrict__ qb) {
    int qi = blockIdx.x, h = blockIdx.y;
    int t = threadIdx.x;            // 128, one token each
    size_t row = (size_t)h*LL + (size_t)qi*BQ + t;
    const float* rp = q + row * DD;
    float x[DD]; float n2 = 0.f;
    #pragma unroll
    for (int d = 0; d < DD; d += 4) {
        float4 v4 = *(const float4*)(rp + d);
        x[d]=v4.x; x[d+1]=v4.y; x[d+2]=v4.z; x[d+3]=v4.w;
        n2 += v4.x*v4.x + v4.y*v4.y + v4.z*v4.z + v4.w*v4.w;
    }
    // fused convert: qb = bf16(q * QSCALE)
    #pragma unroll
    for (int d = 0; d < DD; d += 4) {
        ushort4 o;
        o.x = f2bf(x[d]*QSCALE);   o.y = f2bf(x[d+1]*QSCALE);
        o.z = f2bf(x[d+2]*QSCALE); o.w = f2bf(x[d+3]*QSCALE);
        *(ushort4*)(qb + row*DD + d) = o;
    }
    __shared__ float xs[BQ][DD+1];
    #pragma unroll
    for (int d = 0; d < DD; ++d) xs[t][d] = x[d];
    __syncthreads();
    __shared__ float mean[DD];
    if (t < DD) {
        float s = 0.f;
        for (int r = 0; r < BQ; ++r) s += xs[r][t];
        mean[t] = s * (1.0f/BQ);
    }
    __syncthreads();
    float dot = 0.f, m2 = 0.f;
    #pragma unroll
    for (int d = 0; d < DD; ++d) { dot += x[d]*mean[d]; m2 += mean[d]*mean[d]; }
    float cs = dot / ((sqrtf(n2) + 1e-6f) * (sqrtf(m2) + 1e-6f));
    __shared__ float red[BQ];
    red[t] = cs; __syncthreads();
    for (int sft = BQ/2; sft > 0; sft >>= 1) {
        if (t < sft) red[t] += red[t + sft];
        __syncthreads();
    }
    if (t == 0) compq[h*NQ + qi] = (red[0] * (1.0f/BQ)) > simth[h] ? 1 : 0;
    if (t < DD) qm[((size_t)h*NQ + qi)*DD + t] = mean[t];
}

// ---------------- kernel 2b: k stats + k/vT bf16 convert (fused) ----------------
__global__ void kstat_kernel(const float* __restrict__ k, const float* __restrict__ v,
                             const float* __restrict__ kpart, const float* __restrict__ simth,
                             float* __restrict__ km, int* __restrict__ compk,
                             ushort* __restrict__ kb, ushort* __restrict__ vTb) {
    int ki = blockIdx.x, h = blockIdx.y;   // ki: k-block / 64-token chunk
    int t = threadIdx.x;                   // 64, one token each
    __shared__ float mu_s[DD];
    {
        float s = 0.f;
        #pragma unroll
        for (int b = 0; b < 8; ++b) s += kpart[((size_t)h*8 + b)*64 + t];
        mu_s[t] = s * (1.0f/LL);
    }
    __syncthreads();
    size_t row = (size_t)h*LL + (size_t)ki*BK + t;
    const float* rp = k + row * DD;
    float x[DD]; float n2 = 0.f;
    #pragma unroll
    for (int d = 0; d < DD; d += 4) {
        float4 v4 = *(const float4*)(rp + d);
        v4.x -= mu_s[d]; v4.y -= mu_s[d+1]; v4.z -= mu_s[d+2]; v4.w -= mu_s[d+3];
        x[d]=v4.x; x[d+1]=v4.y; x[d+2]=v4.z; x[d+3]=v4.w;
        n2 += v4.x*v4.x + v4.y*v4.y + v4.z*v4.z + v4.w*v4.w;
    }
    // fused convert: kb = bf16(k - mu)
    #pragma unroll
    for (int d = 0; d < DD; d += 4) {
        ushort4 o;
        o.x = f2bf(x[d]);   o.y = f2bf(x[d+1]);
        o.z = f2bf(x[d+2]); o.w = f2bf(x[d+3]);
        *(ushort4*)(kb + row*DD + d) = o;
    }
    // fused v transpose: load v row -> LDS bf16 tile -> write vTb[d][tok]
    __shared__ ushort vs[64][66];
    {
        const float* vp = v + row * DD;
        #pragma unroll
        for (int d = 0; d < DD; d += 4) {
            float4 v4 = *(const float4*)(vp + d);
            vs[t][d]   = f2bf(v4.x); vs[t][d+1] = f2bf(v4.y);
            vs[t][d+2] = f2bf(v4.z); vs[t][d+3] = f2bf(v4.w);
        }
    }
    __shared__ float xs[BK][DD+1];
    #pragma unroll
    for (int d = 0; d < DD; ++d) xs[t][d] = x[d];
    __syncthreads();
    {   // thread t owns dim d=t: write vTb row
        size_t vbase = ((size_t)h*DD + t)*LL + (size_t)ki*64;
        #pragma unroll
        for (int r8 = 0; r8 < 64; r8 += 8) {
            s8v o;
            #pragma unroll
            for (int e = 0; e < 8; ++e) o[e] = (short)vs[r8+e][t];
            *(s8v*)(vTb + vbase + r8) = o;
        }
    }
    __shared__ float mean[DD];
    {
        float s = 0.f;
        for (int r = 0; r < BK; ++r) s += xs[r][t];
        mean[t] = s * (1.0f/BK);
    }
    __syncthreads();
    float dot = 0.f, m2 = 0.f;
    #pragma unroll
    for (int d = 0; d < DD; ++d) { dot += x[d]*mean[d]; m2 += mean[d]*mean[d]; }
    float cs = dot / ((sqrtf(n2) + 1e-6f) * (sqrtf(m2) + 1e-6f));
    __shared__ float red[BK];
    red[t] = cs; __syncthreads();
    for (int sft = BK/2; sft > 0; sft >>= 1) {
        if (t < sft) red[t] += red[t + sft];
        __syncthreads();
    }
    if (t == 0) compk[h*NK + ki] = (red[0] * (1.0f/BK)) > simth[h] ? 1 : 0;
    km[((size_t)h*NK + ki)*DD + t] = mean[t];
}

// ---------------- kernel 3: block softmax + CDF selection -> packed bitmask ----------------
__global__ void bmask_kernel(const float* __restrict__ qm, const float* __restrict__ km,
                             const int* __restrict__ compq, const int* __restrict__ compk,
                             const float* __restrict__ cdfth, unsigned* __restrict__ bmaskbits) {
    int qi = blockIdx.x, h = blockIdx.y;
    int j = threadIdx.x;            // 32
    __shared__ float ssh[NK];
    __shared__ float p[NK];
    const float* qv = qm + ((size_t)h*NQ + qi)*DD;
    const float* kv = km + ((size_t)h*NK + j)*DD;
    float s = 0.f;
    for (int d = 0; d < DD; ++d) s += qv[d]*kv[d];
    ssh[j] = s * SCALE;
    __syncthreads();
    float m = ssh[0];
    for (int i = 1; i < NK; ++i) m = fmaxf(m, ssh[i]);
    float den = 0.f;
    for (int i = 0; i < NK; ++i) den += expf(ssh[i] - m);
    p[j] = expf(ssh[j] - m) / den;
    __syncthreads();
    float pj = p[j];
    float mass = 0.f;
    for (int i = 0; i < NK; ++i) {
        float pi = p[i];
        if (pi > pj || (pi == pj && i < j)) mass += pi;
    }
    int sel = (mass < cdfth[h]) ? 1 : 0;
    int keep = (sel || !(compq[h*NQ+qi] && compk[h*NK+j])) ? 1 : 0;
    unsigned long long bal = __ballot(keep);
    if (j == 0) bmaskbits[h*NQ + qi] = (unsigned)bal;
}

// ---------------- kernel 4: masked flash attention, swapped-QK^T MFMA ----------------
// Block = 256 thr (4 waves) per (h, qi, half). Wave w owns q-rows
// [qi*128 + half*64 + w*16, +16). Double-buffered LDS K/V staged via
// global_load_lds with source-swizzled addrs (as round 5, verified).
// QK^T computed swapped: S^T = mfma(A=K, B=Q) -> lane (hi,lo) holds
// S[q=lo][k=ni*16+hi*4+r]. Softmax per-lane scalar (m,l); P packed with
// v_cvt_pk_bf16_f32 and stored via 4x ds_write_b64; PV reads P as A-frag.
__global__ __launch_bounds__(256, 2) void attn_kernel(
        const ushort* __restrict__ qb, const ushort* __restrict__ kb,
        const ushort* __restrict__ vTb, const unsigned* __restrict__ bmaskbits,
        float* __restrict__ out) {
    __shared__ __align__(16) ushort ldsK[2][64*64];   // 2 x 8 KB
    __shared__ __align__(16) ushort ldsV[2][64*64];   // 2 x 8 KB
    __shared__ __align__(16) ushort plds[4][16][72];  // per-wave P tile [q][k]

    int h    = blockIdx.y;
    int qi   = blockIdx.x >> 1;
    int half = blockIdx.x & 1;
    int tid  = threadIdx.x;
    int w    = tid >> 6;
    int l    = tid & 63;
    int lo = l & 15, hi = l >> 4;
    int r0 = qi*BQ + half*64 + w*16;

    unsigned msk = bmaskbits[h*NQ + qi];

    const ushort* qh = qb  + (size_t)h*LL*DD;
    const char*   kh = (const char*)(kb  + (size_t)h*LL*DD);   // block j at +j*8192B
    const char*   vh = (const char*)(vTb + (size_t)h*DD*LL);   // row d at +d*4096B; block j at +j*128B

    // ---- staging source offsets (per lane, bytes) ----
    int srow = l >> 3;                       // row within 8-row chunk
    int sgx  = ((l & 7) ^ srow) * 16;        // source 16B-group (inverse swizzle)
    int c0 = 2*w, c1 = 2*w + 1;              // this wave's chunks
    size_t ks0 = (size_t)(c0*8 + srow)*128 + sgx;
    size_t ks1 = (size_t)(c1*8 + srow)*128 + sgx;
    size_t vs0 = (size_t)(c0*8 + srow)*(LL*2) + sgx;
    size_t vs1 = (size_t)(c1*8 + srow)*(LL*2) + sgx;
    int dst0 = c0*1024, dst1 = c1*1024;      // uniform LDS byte base (HW adds lane*16)

    // ---- fragment read offsets (ushort index) ----
    int p0 = (hi)     ^ (lo & 7);            // kk=0 swizzled group
    int p1 = (4 + hi) ^ (lo & 7);            // kk=1
    int kidx0 = lo*64 + p0*8;
    int kidx1 = lo*64 + p1*8;

    // Q frags (used as MFMA B operand in swapped QK^T; same registers as A-use)
    s8v qa[2];
    #pragma unroll
    for (int kk = 0; kk < 2; ++kk)
        qa[kk] = *(const s8v*)(qh + (size_t)(r0 + lo)*DD + kk*32 + hi*8);

    f4v O[4];
    float mrun = -1e30f, lrun = 0.f;         // per-lane: q-row = r0 + lo
    #pragma unroll
    for (int nd = 0; nd < 4; ++nd) O[nd] = (f4v){0.f, 0.f, 0.f, 0.f};

    auto stage = [&](int buf, int j) {
        const char* kj = kh + (size_t)j*8192;
        const char* vj = vh + (size_t)j*128;
        char* kd = (char*)&ldsK[buf][0];
        char* vd = (char*)&ldsV[buf][0];
        GLOAD(kj + ks0, kd + dst0);
        GLOAD(kj + ks1, kd + dst1);
        GLOAD(vj + vs0, vd + dst0);
        GLOAD(vj + vs1, vd + dst1);
    };

    auto compute = [&](const ushort* Kb, const ushort* Vb) {
        // S^T[ni]: rows = k-tokens ni*16+hi*4+r, cols = q-row lo
        f4v S[4];
        #pragma unroll
        for (int ni = 0; ni < 4; ++ni) S[ni] = (f4v){0.f, 0.f, 0.f, 0.f};
        __builtin_amdgcn_s_setprio(1);
        #pragma unroll
        for (int ni = 0; ni < 4; ++ni) {
            s8v kf0 = *(const s8v*)(Kb + ni*1024 + kidx0);
            s8v kf1 = *(const s8v*)(Kb + ni*1024 + kidx1);
            S[ni] = __builtin_amdgcn_mfma_f32_16x16x32_bf16(kf0, qa[0], S[ni], 0, 0, 0);
            S[ni] = __builtin_amdgcn_mfma_f32_16x16x32_bf16(kf1, qa[1], S[ni], 0, 0, 0);
        }
        __builtin_amdgcn_s_setprio(0);
        // in-lane max over this lane's 16 k-values, then cross-hi reduce (2 ops)
        float pm;
        {
            float a0 = fmaxf(fmaxf(S[0][0],S[0][1]), fmaxf(S[0][2],S[0][3]));
            float a1 = fmaxf(fmaxf(S[1][0],S[1][1]), fmaxf(S[1][2],S[1][3]));
            float a2 = fmaxf(fmaxf(S[2][0],S[2][1]), fmaxf(S[2][2],S[2][3]));
            float a3 = fmaxf(fmaxf(S[3][0],S[3][1]), fmaxf(S[3][2],S[3][3]));
            pm = fmaxf(fmaxf(a0,a1), fmaxf(a2,a3));
        }
        pm = fmaxf(pm, __shfl_xor(pm, 16));
        pm = fmaxf(pm, __shfl_xor(pm, 32));
        // defer-max (T13): rescale only when max grows by > 8 (log2 domain)
        if (__any(pm > mrun + 8.0f)) {
            float mnew = fmaxf(mrun, pm);
            float alpha = __builtin_amdgcn_exp2f(mrun - mnew);
            lrun *= alpha;
            #pragma unroll
            for (int r = 0; r < 4; ++r) {
                float a = __shfl(alpha, hi*4 + r);   // alpha of q-row hi*4+r
                #pragma unroll
                for (int nd = 0; nd < 4; ++nd) O[nd][r] *= a;
            }
            mrun = mnew;
        }
        // P = exp2(S - mrun), in-lane partial row-sum
        f4v P4[4];
        float ps = 0.f;
        #pragma unroll
        for (int ni = 0; ni < 4; ++ni)
            #pragma unroll
            for (int r = 0; r < 4; ++r) {
                float p = __builtin_amdgcn_exp2f(S[ni][r] - mrun);
                P4[ni][r] = p;
                ps += p;
            }
        lrun += ps;
        // pack P -> plds[q=lo][k], 4x ds_write_b64
        #pragma unroll
        for (int ni = 0; ni < 4; ++ni) {
            unsigned c01, c23;
            asm("v_cvt_pk_bf16_f32 %0, %1, %2" : "=v"(c01) : "v"(P4[ni][0]), "v"(P4[ni][1]));
            asm("v_cvt_pk_bf16_f32 %0, %1, %2" : "=v"(c23) : "v"(P4[ni][2]), "v"(P4[ni][3]));
            *(uint2*)&plds[w][lo][ni*16 + hi*4] = make_uint2(c01, c23);
        }
        // PV: O += P(16x64) . V^T; P as A-frag from plds
        __builtin_amdgcn_s_setprio(1);
        #pragma unroll
        for (int kk = 0; kk < 2; ++kk) {
            s8v pa = *(const s8v*)&plds[w][lo][kk*32 + hi*8];
            int kidx = kk ? kidx1 : kidx0;
            #pragma unroll
            for (int nd = 0; nd < 4; ++nd) {
                s8v vf = *(const s8v*)(Vb + nd*1024 + kidx);
                O[nd] = __builtin_amdgcn_mfma_f32_16x16x32_bf16(pa, vf, O[nd], 0, 0, 0);
            }
        }
        __builtin_amdgcn_s_setprio(0);
    };

    // ---- 2-phase double-buffered main loop (msk uniform across block) ----
    int j0 = __ffs(msk) - 1; msk &= msk - 1;
    stage(0, j0);
    for (;;) {
        __syncthreads();                      // drains vmcnt: buf0 ready, buf1 free
        int jn = msk ? __ffs(msk) - 1 : -1; msk &= msk - 1;
        if (jn >= 0) stage(1, jn);
        compute(&ldsK[0][0], &ldsV[0][0]);
        if (jn < 0) break;
        __syncthreads();
        int jm = msk ? __ffs(msk) - 1 : -1; msk &= msk - 1;
        if (jm >= 0) stage(0, jm);
        compute(&ldsK[1][0], &ldsV[1][0]);
        if (jm < 0) break;
    }

    // epilogue: total row-sum per q (cross-hi), redistribute to O rows, store
    float ltot = lrun;
    ltot += __shfl_xor(ltot, 16);
    ltot += __shfl_xor(ltot, 32);
    #pragma unroll
    for (int r = 0; r < 4; ++r) {
        float lr = __shfl(ltot, hi*4 + r);    // row-sum of q-row hi*4+r
        float inv = 1.0f / lr;
        int row = r0 + hi*4 + r;
        float* orow = out + ((size_t)h*LL + row)*DD;
        #pragma unroll
        for (int nd = 0; nd < 4; ++nd)
            orow[nd*16 + lo] = O[nd][r] * inv;
    }
}

extern "C" void kernel_launch(void* const* d_in, const int* in_sizes, int n_in,
                              void* d_out, int out_size, void* d_ws, size_t ws_size,
                              hipStream_t stream) {
    const float* q     = (const float*)d_in[0];
    const float* k     = (const float*)d_in[1];
    const float* v     = (const float*)d_in[2];
    const float* simth = (const float*)d_in[3];
    const float* cdfth = (const float*)d_in[4];
    float* out = (float*)d_out;

    float* ws    = (float*)d_ws;
    float* kpart = ws;                       // 16*8*64
    float* qm    = kpart + HH*8*64;          // 16*16*64
    float* km    = qm + HH*NQ*DD;            // 16*32*64
    int*   compq = (int*)(km + HH*NK*DD);    // 256
    int*   compk = compq + HH*NQ;            // 512
    unsigned* bmb = (unsigned*)(compk + HH*NK);  // 256
    size_t off = (size_t)((char*)(bmb + HH*NQ) - (char*)d_ws);
    off = (off + 15) & ~(size_t)15;
    ushort* qbuf = (ushort*)((char*)d_ws + off);
    ushort* kbuf = qbuf + (size_t)HH*LL*DD;
    ushort* vTb  = kbuf + (size_t)HH*LL*DD;

    kmean1_kernel<<<dim3(8, HH), 256, 0, stream>>>(k, kpart);
    qstat_kernel<<<dim3(NQ, HH), BQ, 0, stream>>>(q, simth, qm, compq, qbuf);
    kstat_kernel<<<dim3(NK, HH), BK, 0, stream>>>(k, v, kpart, simth, km, compk, kbuf, vTb);
    bmask_kernel<<<dim3(NQ, HH), NK, 0, stream>>>(qm, km, compq, compk, cdfth, bmb);
    attn_kernel<<<dim3(NQ*2, HH), 256, 0, stream>>>(qbuf, kbuf, vTb, bmb, out);
}

// Round 7
// 78.230 us; speedup vs baseline: 1.5393x; 1.0457x over previous
//
#include <hip/hip_runtime.h>

#define HH 16
#define LL 2048
#define DD 64
#define BQ 128
#define BK 64
#define NQ (LL/BQ)   /* 16 */
#define NK (LL/BK)   /* 32 */
#define SCALE 0.125f
#define QSCALE (0.125f * 1.44269504f)   /* fold log2(e): softmax via exp2 */

typedef __attribute__((ext_vector_type(8))) short s8v;   // 8 bf16 (4 VGPR)
typedef __attribute__((ext_vector_type(4))) float f4v;   // 4 fp32 acc

static __device__ __forceinline__ ushort f2bf(float x) {
    unsigned u = __float_as_uint(x);
    u += 0x7fff + ((u >> 16) & 1);       // round-to-nearest-even
    return (ushort)(u >> 16);
}

// async global->LDS, 16B per lane; LDS dest = uniform base + lane*16
#define GLOAD(src, dst) \
    __builtin_amdgcn_global_load_lds((const __attribute__((address_space(1))) unsigned int*)(src), \
                                     (__attribute__((address_space(3))) unsigned int*)(dst), 16, 0, 0)

#define VMWAIT4 do { asm volatile("s_waitcnt vmcnt(4)" ::: "memory"); __builtin_amdgcn_sched_barrier(0); } while(0)
#define VMWAIT0 do { asm volatile("s_waitcnt vmcnt(0)" ::: "memory"); __builtin_amdgcn_sched_barrier(0); } while(0)
#define BARRIER do { __builtin_amdgcn_s_barrier(); __builtin_amdgcn_sched_barrier(0); } while(0)

// ---------------- kernel 1: per-head k partial sums ----------------
__global__ void kmean1_kernel(const float* __restrict__ k, float* __restrict__ kpart) {
    int b = blockIdx.x;             // 0..7 token slab of 256
    int h = blockIdx.y;
    int t = threadIdx.x;            // 256
    int d = t & 63, c = t >> 6;
    const float* kh = k + ((size_t)h*LL + (size_t)b*256) * DD;
    float s = 0.f;
    for (int l = c*64; l < c*64 + 64; ++l) s += kh[(size_t)l * DD + d];
    __shared__ float red[4][64];
    red[c][d] = s;
    __syncthreads();
    if (t < 64) kpart[((size_t)h*8 + b)*64 + t] = red[0][t]+red[1][t]+red[2][t]+red[3][t];
}

// ---------------- kernel 2: fused stats + bf16 converts ----------------
// blockIdx.x < NQ: q-block stats + qb convert (128 thr, one token each)
// else: k-block stats + kb convert + vT convert (128 thr; 64 for k, 64 for v)
__global__ __launch_bounds__(128) void stats_kernel(
        const float* __restrict__ q, const float* __restrict__ k, const float* __restrict__ v,
        const float* __restrict__ kpart, const float* __restrict__ simth,
        float* __restrict__ qm, float* __restrict__ km,
        int* __restrict__ compq, int* __restrict__ compk,
        ushort* __restrict__ qb, ushort* __restrict__ kb, ushort* __restrict__ vTb) {
    __shared__ __align__(16) char smem[34304];
    int h = blockIdx.y, t = threadIdx.x;

    if ((int)blockIdx.x < NQ) {
        // ---------- q path ----------
        int qi = blockIdx.x;
        float (*xs)[DD+1] = (float(*)[DD+1])smem;         // 128*65*4 = 33280
        float* mean = (float*)(smem + 33280);             // 256
        float* red  = (float*)(smem + 33536);             // 512
        size_t row = (size_t)h*LL + (size_t)qi*BQ + t;
        const float* rp = q + row * DD;
        float x[DD]; float n2 = 0.f;
        #pragma unroll
        for (int d = 0; d < DD; d += 4) {
            float4 v4 = *(const float4*)(rp + d);
            x[d]=v4.x; x[d+1]=v4.y; x[d+2]=v4.z; x[d+3]=v4.w;
            n2 += v4.x*v4.x + v4.y*v4.y + v4.z*v4.z + v4.w*v4.w;
        }
        #pragma unroll
        for (int d = 0; d < DD; d += 4) {
            ushort4 o;
            o.x = f2bf(x[d]*QSCALE);   o.y = f2bf(x[d+1]*QSCALE);
            o.z = f2bf(x[d+2]*QSCALE); o.w = f2bf(x[d+3]*QSCALE);
            *(ushort4*)(qb + row*DD + d) = o;
        }
        #pragma unroll
        for (int d = 0; d < DD; ++d) xs[t][d] = x[d];
        __syncthreads();
        if (t < DD) {
            float s = 0.f;
            for (int r = 0; r < BQ; ++r) s += xs[r][t];
            mean[t] = s * (1.0f/BQ);
        }
        __syncthreads();
        float dot = 0.f, m2 = 0.f;
        #pragma unroll
        for (int d = 0; d < DD; ++d) { dot += x[d]*mean[d]; m2 += mean[d]*mean[d]; }
        float cs = dot / ((sqrtf(n2) + 1e-6f) * (sqrtf(m2) + 1e-6f));
        red[t] = cs; __syncthreads();
        for (int sft = BQ/2; sft > 0; sft >>= 1) {
            if (t < sft) red[t] += red[t + sft];
            __syncthreads();
        }
        if (t == 0) compq[h*NQ + qi] = (red[0] * (1.0f/BQ)) > simth[h] ? 1 : 0;
        if (t < DD) qm[((size_t)h*NQ + qi)*DD + t] = mean[t];
    } else {
        // ---------- k/v path ----------
        int ki = blockIdx.x - NQ;
        float* mu_s = (float*)smem;                               // 256
        float (*xs)[DD+1] = (float(*)[DD+1])(smem + 256);         // 64*65*4 = 16640
        ushort (*vs)[66]  = (ushort(*)[66])(smem + 256 + 16640);  // 8448
        float* mean = (float*)(smem + 256 + 16640 + 8448);        // 256
        float* red  = (float*)(smem + 256 + 16640 + 8448 + 256);  // 256
        if (t < 64) {
            float s = 0.f;
            #pragma unroll
            for (int b = 0; b < 8; ++b) s += kpart[((size_t)h*8 + b)*64 + t];
            mu_s[t] = s * (1.0f/LL);
        }
        __syncthreads();
        size_t rowb = (size_t)h*LL + (size_t)ki*BK;
        float x[DD]; float n2 = 0.f;
        if (t < 64) {
            const float* rp = k + (rowb + t) * DD;
            #pragma unroll
            for (int d = 0; d < DD; d += 4) {
                float4 v4 = *(const float4*)(rp + d);
                v4.x -= mu_s[d]; v4.y -= mu_s[d+1]; v4.z -= mu_s[d+2]; v4.w -= mu_s[d+3];
                x[d]=v4.x; x[d+1]=v4.y; x[d+2]=v4.z; x[d+3]=v4.w;
                n2 += v4.x*v4.x + v4.y*v4.y + v4.z*v4.z + v4.w*v4.w;
            }
            #pragma unroll
            for (int d = 0; d < DD; d += 4) {
                ushort4 o;
                o.x = f2bf(x[d]);   o.y = f2bf(x[d+1]);
                o.z = f2bf(x[d+2]); o.w = f2bf(x[d+3]);
                *(ushort4*)(kb + (rowb + t)*DD + d) = o;
            }
            #pragma unroll
            for (int d = 0; d < DD; ++d) xs[t][d] = x[d];
        } else {
            int tk = t - 64;
            const float* vp = v + (rowb + tk) * DD;
            #pragma unroll
            for (int d = 0; d < DD; d += 4) {
                float4 v4 = *(const float4*)(vp + d);
                vs[tk][d]   = f2bf(v4.x); vs[tk][d+1] = f2bf(v4.y);
                vs[tk][d+2] = f2bf(v4.z); vs[tk][d+3] = f2bf(v4.w);
            }
        }
        __syncthreads();
        if (t < 64) {
            // vT write: thread t owns dim d = t
            size_t vbase = ((size_t)h*DD + t)*LL + (size_t)ki*64;
            #pragma unroll
            for (int r8 = 0; r8 < 64; r8 += 8) {
                s8v o;
                #pragma unroll
                for (int e = 0; e < 8; ++e) o[e] = (short)vs[r8+e][t];
                *(s8v*)(vTb + vbase + r8) = o;
            }
            float s = 0.f;
            for (int r = 0; r < BK; ++r) s += xs[r][t];
            mean[t] = s * (1.0f/BK);
        }
        __syncthreads();
        if (t < 64) {
            float dot = 0.f, m2 = 0.f;
            #pragma unroll
            for (int d = 0; d < DD; ++d) { dot += x[d]*mean[d]; m2 += mean[d]*mean[d]; }
            float cs = dot / ((sqrtf(n2) + 1e-6f) * (sqrtf(m2) + 1e-6f));
            red[t] = cs;
        }
        __syncthreads();
        for (int sft = 32; sft > 0; sft >>= 1) {
            if (t < sft) red[t] += red[t + sft];
            __syncthreads();
        }
        if (t == 0) compk[h*NK + ki] = (red[0] * (1.0f/BK)) > simth[h] ? 1 : 0;
        if (t < 64) km[((size_t)h*NK + ki)*DD + t] = mean[t];
    }
}

// ---------------- kernel 3: masked flash attention, swapped-QK^T MFMA ----------------
// Block = 256 thr (4 waves) per (h, qi, half). Inline bmask (wave 0, math
// bit-identical to old bmask kernel). Triple-buffered LDS K/V with counted
// vmcnt(4) + raw s_barrier: stage(buf) issued AFTER the barrier proving buf
// consumed; wait only the oldest outstanding stage. Uniform msk -> uniform flow.
__global__ __launch_bounds__(256, 2) void attn_kernel(
        const ushort* __restrict__ qb, const ushort* __restrict__ kb,
        const ushort* __restrict__ vTb,
        const float* __restrict__ qm, const float* __restrict__ km,
        const int* __restrict__ compq, const int* __restrict__ compk,
        const float* __restrict__ cdfth, float* __restrict__ out) {
    __shared__ __align__(16) ushort ldsK[3][64*64];   // 3 x 8 KB
    __shared__ __align__(16) ushort ldsV[3][64*64];   // 3 x 8 KB
    __shared__ __align__(16) ushort plds[4][16][72];  // per-wave P tile [q][k]
    __shared__ unsigned mskS;

    int h    = blockIdx.y;
    int qi   = blockIdx.x >> 1;
    int half = blockIdx.x & 1;
    int tid  = threadIdx.x;
    int w    = tid >> 6;
    int l    = tid & 63;
    int lo = l & 15, hi = l >> 4;
    int r0 = qi*BQ + half*64 + w*16;

    const ushort* qh = qb  + (size_t)h*LL*DD;
    const char*   kh = (const char*)(kb  + (size_t)h*LL*DD);   // block j at +j*8192B
    const char*   vh = (const char*)(vTb + (size_t)h*DD*LL);   // row d at +d*4096B; block j at +j*128B

    // Q frags issued early (latency hides under mask compute)
    s8v qa[2];
    #pragma unroll
    for (int kk = 0; kk < 2; ++kk)
        qa[kk] = *(const s8v*)(qh + (size_t)(r0 + lo)*DD + kk*32 + hi*8);

    // ---- inline bmask (wave 0); bit-identical to the old bmask kernel ----
    if (tid < 64) {
        int j = l & 31;
        const float* qv = qm + ((size_t)h*NQ + qi)*DD;
        const float* kv = km + ((size_t)h*NK + j)*DD;
        float s = 0.f;
        for (int d = 0; d < DD; ++d) s += qv[d]*kv[d];
        s *= SCALE;
        float m = s;
        #pragma unroll
        for (int xm = 1; xm <= 16; xm <<= 1) m = fmaxf(m, __shfl_xor(m, xm, 32));
        float e = expf(s - m);
        float den = 0.f;
        for (int i = 0; i < 32; ++i) den += __shfl(e, i, 32);   // ascending, exact
        float p = e / den;
        float mass = 0.f;
        for (int i = 0; i < 32; ++i) {
            float pi = __shfl(p, i, 32);
            if (pi > p || (pi == p && i < j)) mass += pi;
        }
        int keep = (mass < cdfth[h]) || !(compq[h*NQ+qi] && compk[h*NK+j]);
        unsigned long long bal = __ballot(keep != 0);
        if (l == 0) mskS = (unsigned)bal;
    }
    __syncthreads();
    unsigned msk = mskS;

    // ---- staging source offsets (per lane, bytes) ----
    int srow = l >> 3;                       // row within 8-row chunk
    int sgx  = ((l & 7) ^ srow) * 16;        // source 16B-group (inverse swizzle)
    int c0 = 2*w, c1 = 2*w + 1;              // this wave's chunks
    size_t ks0 = (size_t)(c0*8 + srow)*128 + sgx;
    size_t ks1 = (size_t)(c1*8 + srow)*128 + sgx;
    size_t vs0 = (size_t)(c0*8 + srow)*(LL*2) + sgx;
    size_t vs1 = (size_t)(c1*8 + srow)*(LL*2) + sgx;
    int dst0 = c0*1024, dst1 = c1*1024;      // uniform LDS byte base (HW adds lane*16)

    // ---- fragment read offsets (ushort index) ----
    int p0 = (hi)     ^ (lo & 7);            // kk=0 swizzled group
    int p1 = (4 + hi) ^ (lo & 7);            // kk=1
    int kidx0 = lo*64 + p0*8;
    int kidx1 = lo*64 + p1*8;

    f4v O[4];
    float mrun = -1e30f, lrun = 0.f;         // per-lane: q-row = r0 + lo
    #pragma unroll
    for (int nd = 0; nd < 4; ++nd) O[nd] = (f4v){0.f, 0.f, 0.f, 0.f};

    auto stage = [&](int buf, int j) {
        const char* kj = kh + (size_t)j*8192;
        const char* vj = vh + (size_t)j*128;
        char* kd = (char*)&ldsK[buf][0];
        char* vd = (char*)&ldsV[buf][0];
        GLOAD(kj + ks0, kd + dst0);
        GLOAD(kj + ks1, kd + dst1);
        GLOAD(vj + vs0, vd + dst0);
        GLOAD(vj + vs1, vd + dst1);
    };

    auto compute = [&](const ushort* Kb, const ushort* Vb) {
        f4v S[4];
        #pragma unroll
        for (int ni = 0; ni < 4; ++ni) S[ni] = (f4v){0.f, 0.f, 0.f, 0.f};
        __builtin_amdgcn_s_setprio(1);
        #pragma unroll
        for (int ni = 0; ni < 4; ++ni) {
            s8v kf0 = *(const s8v*)(Kb + ni*1024 + kidx0);
            s8v kf1 = *(const s8v*)(Kb + ni*1024 + kidx1);
            S[ni] = __builtin_amdgcn_mfma_f32_16x16x32_bf16(kf0, qa[0], S[ni], 0, 0, 0);
            S[ni] = __builtin_amdgcn_mfma_f32_16x16x32_bf16(kf1, qa[1], S[ni], 0, 0, 0);
        }
        __builtin_amdgcn_s_setprio(0);
        float pm;
        {
            float a0 = fmaxf(fmaxf(S[0][0],S[0][1]), fmaxf(S[0][2],S[0][3]));
            float a1 = fmaxf(fmaxf(S[1][0],S[1][1]), fmaxf(S[1][2],S[1][3]));
            float a2 = fmaxf(fmaxf(S[2][0],S[2][1]), fmaxf(S[2][2],S[2][3]));
            float a3 = fmaxf(fmaxf(S[3][0],S[3][1]), fmaxf(S[3][2],S[3][3]));
            pm = fmaxf(fmaxf(a0,a1), fmaxf(a2,a3));
        }
        pm = fmaxf(pm, __shfl_xor(pm, 16));
        pm = fmaxf(pm, __shfl_xor(pm, 32));
        if (__any(pm > mrun + 8.0f)) {       // defer-max (T13)
            float mnew = fmaxf(mrun, pm);
            float alpha = __builtin_amdgcn_exp2f(mrun - mnew);
            lrun *= alpha;
            #pragma unroll
            for (int r = 0; r < 4; ++r) {
                float a = __shfl(alpha, hi*4 + r);
                #pragma unroll
                for (int nd = 0; nd < 4; ++nd) O[nd][r] *= a;
            }
            mrun = mnew;
        }
        f4v P4[4];
        float ps = 0.f;
        #pragma unroll
        for (int ni = 0; ni < 4; ++ni)
            #pragma unroll
            for (int r = 0; r < 4; ++r) {
                float p = __builtin_amdgcn_exp2f(S[ni][r] - mrun);
                P4[ni][r] = p;
                ps += p;
            }
        lrun += ps;
        #pragma unroll
        for (int ni = 0; ni < 4; ++ni) {
            unsigned c01, c23;
            asm("v_cvt_pk_bf16_f32 %0, %1, %2" : "=v"(c01) : "v"(P4[ni][0]), "v"(P4[ni][1]));
            asm("v_cvt_pk_bf16_f32 %0, %1, %2" : "=v"(c23) : "v"(P4[ni][2]), "v"(P4[ni][3]));
            *(uint2*)&plds[w][lo][ni*16 + hi*4] = make_uint2(c01, c23);
        }
        __builtin_amdgcn_s_setprio(1);
        #pragma unroll
        for (int kk = 0; kk < 2; ++kk) {
            s8v pa = *(const s8v*)&plds[w][lo][kk*32 + hi*8];
            int kidx = kk ? kidx1 : kidx0;
            #pragma unroll
            for (int nd = 0; nd < 4; ++nd) {
                s8v vf = *(const s8v*)(Vb + nd*1024 + kidx);
                O[nd] = __builtin_amdgcn_mfma_f32_16x16x32_bf16(pa, vf, O[nd], 0, 0, 0);
            }
        }
        __builtin_amdgcn_s_setprio(0);
    };

    // ---- depth-2 pipelined main loop (3 buffers, counted vmcnt) ----
    int ja = __ffs(msk) - 1; msk &= msk - 1;      // mask always nonzero (top-1 kept)
    stage(0, ja);
    int jb = msk ? __ffs(msk) - 1 : -1; msk &= msk - 1;
    if (jb >= 0) stage(1, jb);
    int jc;
    for (;;) {
        // phase A: compute buf0; stage buf2
        if (jb >= 0) { VMWAIT4; } else { VMWAIT0; }
        BARRIER;
        jc = msk ? __ffs(msk) - 1 : -1; msk &= msk - 1;
        if (jc >= 0) stage(2, jc);
        compute(&ldsK[0][0], &ldsV[0][0]);
        if (jb < 0) break;
        // phase B: compute buf1; stage buf0
        if (jc >= 0) { VMWAIT4; } else { VMWAIT0; }
        BARRIER;
        ja = msk ? __ffs(msk) - 1 : -1; msk &= msk - 1;
        if (ja >= 0) stage(0, ja);
        compute(&ldsK[1][0], &ldsV[1][0]);
        if (jc < 0) break;
        // phase C: compute buf2; stage buf1
        if (ja >= 0) { VMWAIT4; } else { VMWAIT0; }
        BARRIER;
        jb = msk ? __ffs(msk) - 1 : -1; msk &= msk - 1;
        if (jb >= 0) stage(1, jb);
        compute(&ldsK[2][0], &ldsV[2][0]);
        if (ja < 0) break;
    }

    // epilogue: total row-sum per q (cross-hi), redistribute to O rows, store
    float ltot = lrun;
    ltot += __shfl_xor(ltot, 16);
    ltot += __shfl_xor(ltot, 32);
    #pragma unroll
    for (int r = 0; r < 4; ++r) {
        float lr = __shfl(ltot, hi*4 + r);
        float inv = 1.0f / lr;
        int row = r0 + hi*4 + r;
        float* orow = out + ((size_t)h*LL + row)*DD;
        #pragma unroll
        for (int nd = 0; nd < 4; ++nd)
            orow[nd*16 + lo] = O[nd][r] * inv;
    }
}

extern "C" void kernel_launch(void* const* d_in, const int* in_sizes, int n_in,
                              void* d_out, int out_size, void* d_ws, size_t ws_size,
                              hipStream_t stream) {
    const float* q     = (const float*)d_in[0];
    const float* k     = (const float*)d_in[1];
    const float* v     = (const float*)d_in[2];
    const float* simth = (const float*)d_in[3];
    const float* cdfth = (const float*)d_in[4];
    float* out = (float*)d_out;

    float* ws    = (float*)d_ws;
    float* kpart = ws;                       // 16*8*64
    float* qm    = kpart + HH*8*64;          // 16*16*64
    float* km    = qm + HH*NQ*DD;            // 16*32*64
    int*   compq = (int*)(km + HH*NK*DD);    // 256
    int*   compk = compq + HH*NQ;            // 512
    size_t off = (size_t)((char*)(compk + HH*NK) - (char*)d_ws);
    off = (off + 15) & ~(size_t)15;
    ushort* qbuf = (ushort*)((char*)d_ws + off);
    ushort* kbuf = qbuf + (size_t)HH*LL*DD;
    ushort* vTb  = kbuf + (size_t)HH*LL*DD;

    kmean1_kernel<<<dim3(8, HH), 256, 0, stream>>>(k, kpart);
    stats_kernel<<<dim3(NQ + NK, HH), 128, 0, stream>>>(q, k, v, kpart, simth,
                                                        qm, km, compq, compk,
                                                        qbuf, kbuf, vTb);
    attn_kernel<<<dim3(NQ*2, HH), 256, 0, stream>>>(qbuf, kbuf, vTb,
                                                    qm, km, compq, compk, cdfth, out);
}

// Round 8
// 75.285 us; speedup vs baseline: 1.5995x; 1.0391x over previous
//
#include <hip/hip_runtime.h>

#define HH 16
#define LL 2048
#define DD 64
#define BQ 128
#define BK 64
#define NQ (LL/BQ)   /* 16 */
#define NK (LL/BK)   /* 32 */
#define SCALE 0.125f
#define QSCALE (0.125f * 1.44269504f)   /* fold log2(e): softmax via exp2 */

typedef __attribute__((ext_vector_type(8))) short s8v;   // 8 bf16 (4 VGPR)
typedef __attribute__((ext_vector_type(4))) float f4v;   // 4 fp32 acc

static __device__ __forceinline__ ushort f2bf(float x) {
    unsigned u = __float_as_uint(x);
    u += 0x7fff + ((u >> 16) & 1);       // round-to-nearest-even
    return (ushort)(u >> 16);
}

// ---------------- kernel 1: per-head k partial sums ----------------
__global__ void kmean1_kernel(const float* __restrict__ k, float* __restrict__ kpart) {
    int b = blockIdx.x;             // 0..7 token slab of 256
    int h = blockIdx.y;
    int t = threadIdx.x;            // 256
    int d = t & 63, c = t >> 6;
    const float* kh = k + ((size_t)h*LL + (size_t)b*256) * DD;
    float s = 0.f;
    for (int l = c*64; l < c*64 + 64; ++l) s += kh[(size_t)l * DD + d];
    __shared__ float red[4][64];
    red[c][d] = s;
    __syncthreads();
    if (t < 64) kpart[((size_t)h*8 + b)*64 + t] = red[0][t]+red[1][t]+red[2][t]+red[3][t];
}

// ---------------- kernel 2: fused stats + bf16 converts ----------------
__global__ __launch_bounds__(128) void stats_kernel(
        const float* __restrict__ q, const float* __restrict__ k, const float* __restrict__ v,
        const float* __restrict__ kpart, const float* __restrict__ simth,
        float* __restrict__ qm, float* __restrict__ km,
        int* __restrict__ compq, int* __restrict__ compk,
        ushort* __restrict__ qb, ushort* __restrict__ kb, ushort* __restrict__ vTb) {
    __shared__ __align__(16) char smem[34304];
    int h = blockIdx.y, t = threadIdx.x;

    if ((int)blockIdx.x < NQ) {
        // ---------- q path ----------
        int qi = blockIdx.x;
        float (*xs)[DD+1] = (float(*)[DD+1])smem;         // 128*65*4 = 33280
        float* mean = (float*)(smem + 33280);             // 256
        float* red  = (float*)(smem + 33536);             // 512
        size_t row = (size_t)h*LL + (size_t)qi*BQ + t;
        const float* rp = q + row * DD;
        float x[DD]; float n2 = 0.f;
        #pragma unroll
        for (int d = 0; d < DD; d += 4) {
            float4 v4 = *(const float4*)(rp + d);
            x[d]=v4.x; x[d+1]=v4.y; x[d+2]=v4.z; x[d+3]=v4.w;
            n2 += v4.x*v4.x + v4.y*v4.y + v4.z*v4.z + v4.w*v4.w;
        }
        #pragma unroll
        for (int d = 0; d < DD; d += 4) {
            ushort4 o;
            o.x = f2bf(x[d]*QSCALE);   o.y = f2bf(x[d+1]*QSCALE);
            o.z = f2bf(x[d+2]*QSCALE); o.w = f2bf(x[d+3]*QSCALE);
            *(ushort4*)(qb + row*DD + d) = o;
        }
        #pragma unroll
        for (int d = 0; d < DD; ++d) xs[t][d] = x[d];
        __syncthreads();
        if (t < DD) {
            float s = 0.f;
            for (int r = 0; r < BQ; ++r) s += xs[r][t];
            mean[t] = s * (1.0f/BQ);
        }
        __syncthreads();
        float dot = 0.f, m2 = 0.f;
        #pragma unroll
        for (int d = 0; d < DD; ++d) { dot += x[d]*mean[d]; m2 += mean[d]*mean[d]; }
        float cs = dot / ((sqrtf(n2) + 1e-6f) * (sqrtf(m2) + 1e-6f));
        red[t] = cs; __syncthreads();
        for (int sft = BQ/2; sft > 0; sft >>= 1) {
            if (t < sft) red[t] += red[t + sft];
            __syncthreads();
        }
        if (t == 0) compq[h*NQ + qi] = (red[0] * (1.0f/BQ)) > simth[h] ? 1 : 0;
        if (t < DD) qm[((size_t)h*NQ + qi)*DD + t] = mean[t];
    } else {
        // ---------- k/v path ----------
        int ki = blockIdx.x - NQ;
        float* mu_s = (float*)smem;                               // 256
        float (*xs)[DD+1] = (float(*)[DD+1])(smem + 256);         // 64*65*4 = 16640
        ushort (*vs)[66]  = (ushort(*)[66])(smem + 256 + 16640);  // 8448
        float* mean = (float*)(smem + 256 + 16640 + 8448);        // 256
        float* red  = (float*)(smem + 256 + 16640 + 8448 + 256);  // 256
        if (t < 64) {
            float s = 0.f;
            #pragma unroll
            for (int b = 0; b < 8; ++b) s += kpart[((size_t)h*8 + b)*64 + t];
            mu_s[t] = s * (1.0f/LL);
        }
        __syncthreads();
        size_t rowb = (size_t)h*LL + (size_t)ki*BK;
        float x[DD]; float n2 = 0.f;
        if (t < 64) {
            const float* rp = k + (rowb + t) * DD;
            #pragma unroll
            for (int d = 0; d < DD; d += 4) {
                float4 v4 = *(const float4*)(rp + d);
                v4.x -= mu_s[d]; v4.y -= mu_s[d+1]; v4.z -= mu_s[d+2]; v4.w -= mu_s[d+3];
                x[d]=v4.x; x[d+1]=v4.y; x[d+2]=v4.z; x[d+3]=v4.w;
                n2 += v4.x*v4.x + v4.y*v4.y + v4.z*v4.z + v4.w*v4.w;
            }
            #pragma unroll
            for (int d = 0; d < DD; d += 4) {
                ushort4 o;
                o.x = f2bf(x[d]);   o.y = f2bf(x[d+1]);
                o.z = f2bf(x[d+2]); o.w = f2bf(x[d+3]);
                *(ushort4*)(kb + (rowb + t)*DD + d) = o;
            }
            #pragma unroll
            for (int d = 0; d < DD; ++d) xs[t][d] = x[d];
        } else {
            int tk = t - 64;
            const float* vp = v + (rowb + tk) * DD;
            #pragma unroll
            for (int d = 0; d < DD; d += 4) {
                float4 v4 = *(const float4*)(vp + d);
                vs[tk][d]   = f2bf(v4.x); vs[tk][d+1] = f2bf(v4.y);
                vs[tk][d+2] = f2bf(v4.z); vs[tk][d+3] = f2bf(v4.w);
            }
        }
        __syncthreads();
        if (t < 64) {
            size_t vbase = ((size_t)h*DD + t)*LL + (size_t)ki*64;
            #pragma unroll
            for (int r8 = 0; r8 < 64; r8 += 8) {
                s8v o;
                #pragma unroll
                for (int e = 0; e < 8; ++e) o[e] = (short)vs[r8+e][t];
                *(s8v*)(vTb + vbase + r8) = o;
            }
            float s = 0.f;
            for (int r = 0; r < BK; ++r) s += xs[r][t];
            mean[t] = s * (1.0f/BK);
        }
        __syncthreads();
        if (t < 64) {
            float dot = 0.f, m2 = 0.f;
            #pragma unroll
            for (int d = 0; d < DD; ++d) { dot += x[d]*mean[d]; m2 += mean[d]*mean[d]; }
            float cs = dot / ((sqrtf(n2) + 1e-6f) * (sqrtf(m2) + 1e-6f));
            red[t] = cs;
        }
        __syncthreads();
        for (int sft = 32; sft > 0; sft >>= 1) {
            if (t < sft) red[t] += red[t + sft];
            __syncthreads();
        }
        if (t == 0) compk[h*NK + ki] = (red[0] * (1.0f/BK)) > simth[h] ? 1 : 0;
        if (t < 64) km[((size_t)h*NK + ki)*DD + t] = mean[t];
    }
}

// ---------------- kernel 3: block softmax + CDF selection -> packed bitmask ----------------
__global__ void bmask_kernel(const float* __restrict__ qm, const float* __restrict__ km,
                             const int* __restrict__ compq, const int* __restrict__ compk,
                             const float* __restrict__ cdfth, unsigned* __restrict__ bmaskbits) {
    int qi = blockIdx.x, h = blockIdx.y;
    int j = threadIdx.x;            // 32
    __shared__ float ssh[NK];
    __shared__ float p[NK];
    const float* qv = qm + ((size_t)h*NQ + qi)*DD;
    const float* kv = km + ((size_t)h*NK + j)*DD;
    float s = 0.f;
    for (int d = 0; d < DD; ++d) s += qv[d]*kv[d];
    ssh[j] = s * SCALE;
    __syncthreads();
    float m = ssh[0];
    for (int i = 1; i < NK; ++i) m = fmaxf(m, ssh[i]);
    float den = 0.f;
    for (int i = 0; i < NK; ++i) den += expf(ssh[i] - m);
    p[j] = expf(ssh[j] - m) / den;
    __syncthreads();
    float pj = p[j];
    float mass = 0.f;
    for (int i = 0; i < NK; ++i) {
        float pi = p[i];
        if (pi > pj || (pi == pj && i < j)) mass += pi;
    }
    int sel = (mass < cdfth[h]) ? 1 : 0;
    int keep = (sel || !(compq[h*NQ+qi] && compk[h*NK+j])) ? 1 : 0;
    unsigned long long bal = __ballot(keep);
    if (j == 0) bmaskbits[h*NQ + qi] = (unsigned)bal;
}

// ---------------- kernel 4: wave-autonomous masked flash attention ----------------
// Block = (h, qi, half), 4 waves, NO barriers in main loop. The 4 waves split
// the selected k-blocks by selection rank (rank%4==w). Each wave per iter:
// 64q x 64k, K/V/Q fragments loaded directly from global (K/V are L2-resident;
// LDS staging removed). P redistributed through a private per-wave LDS tile.
// End: flash-combine of the 4 per-wave partials (m,l,O) via LDS.
// mfma_f32_16x16x32_bf16: A lane(lo,hi)=A[lo][hi*8+j]; B=B[hi*8+j][lo];
// D lane reg r = D[hi*4+r][lo]   (verified rounds 2-7).
__global__ __launch_bounds__(256, 2) void attn_kernel(
        const ushort* __restrict__ qb, const ushort* __restrict__ kb,
        const ushort* __restrict__ vTb, const unsigned* __restrict__ bmaskbits,
        float* __restrict__ out) {
    // LDS: [0,40960) per-wave P tiles [64][80] ushort (main loop),
    //      UNION [0,67584) O-merge [4][64][66] f32 (epilogue),
    //      [67584,68608) m[4][64], [68608,69632) l[4][64]
    __shared__ __align__(16) char shmem[69632];
    ushort* pl = (ushort*)(shmem) + (threadIdx.x >> 6) * 64 * 80;
    float*  Ob = (float*)shmem;                     // stride 4224 floats per wave
    float*  mb = (float*)(shmem + 67584);
    float*  lb = (float*)(shmem + 68608);

    int h    = blockIdx.y;
    int qi   = blockIdx.x >> 1;
    int half = blockIdx.x & 1;
    int tid  = threadIdx.x;
    int w    = tid >> 6;
    int l    = tid & 63;
    int lo = l & 15, hi = l >> 4;
    int r0 = qi*BQ + half*64;                // base of this block's 64 q-rows

    unsigned msk = bmaskbits[h*NQ + qi];

    const ushort* qh = qb  + (size_t)h*LL*DD;
    const ushort* kh = kb  + (size_t)h*LL*DD;
    const ushort* vh = vTb + (size_t)h*DD*LL;

    // Q B-frags for all 4 q-tiles (shared by all waves)
    s8v qf[4][2];
    #pragma unroll
    for (int qt = 0; qt < 4; ++qt)
        #pragma unroll
        for (int kk = 0; kk < 2; ++kk)
            qf[qt][kk] = *(const s8v*)(qh + (size_t)(r0 + qt*16 + lo)*DD + kk*32 + hi*8);

    f4v O[4][4];
    float m[4], lsum[4];
    #pragma unroll
    for (int qt = 0; qt < 4; ++qt) {
        m[qt] = -1e30f; lsum[qt] = 0.f;
        #pragma unroll
        for (int dt = 0; dt < 4; ++dt) O[qt][dt] = (f4v){0.f,0.f,0.f,0.f};
    }

    unsigned mm = msk; int rank = 0;
    while (mm) {
        int j = __ffs(mm) - 1; mm &= mm - 1;
        if (((rank++) & 3) != w) continue;     // rank-split across waves

        const ushort* kbj = kh + (size_t)j*BK*DD;
        const ushort* vbj = vh + (size_t)j*BK;

        // K A-frags direct from global (L2)
        s8v kf[4][2];
        #pragma unroll
        for (int kt = 0; kt < 4; ++kt)
            #pragma unroll
            for (int kk = 0; kk < 2; ++kk)
                kf[kt][kk] = *(const s8v*)(kbj + (size_t)(kt*16 + lo)*DD + kk*32 + hi*8);

        // S^T = K . Q^T : lane holds S[k=kt*16+hi*4+r][q=qt*16+lo]
        f4v S[4][4];
        #pragma unroll
        for (int kt = 0; kt < 4; ++kt)
            #pragma unroll
            for (int qt = 0; qt < 4; ++qt)
                S[kt][qt] = (f4v){0.f,0.f,0.f,0.f};
        __builtin_amdgcn_s_setprio(1);
        #pragma unroll
        for (int kk = 0; kk < 2; ++kk)
            #pragma unroll
            for (int kt = 0; kt < 4; ++kt)
                #pragma unroll
                for (int qt = 0; qt < 4; ++qt)
                    S[kt][qt] = __builtin_amdgcn_mfma_f32_16x16x32_bf16(kf[kt][kk], qf[qt][kk], S[kt][qt], 0, 0, 0);
        __builtin_amdgcn_s_setprio(0);

        // V B-frags issued now; latency hides under softmax + P round-trip
        s8v vf[2][4];
        #pragma unroll
        for (int kk = 0; kk < 2; ++kk)
            #pragma unroll
            for (int dt = 0; dt < 4; ++dt)
                vf[kk][dt] = *(const s8v*)(vbj + (size_t)(dt*16 + lo)*LL + kk*32 + hi*8);

        // per-q (=qt*16+lo) max over this wave's 64 k
        float pm[4];
        #pragma unroll
        for (int qt = 0; qt < 4; ++qt) {
            float a0 = fmaxf(fmaxf(S[0][qt][0],S[0][qt][1]), fmaxf(S[0][qt][2],S[0][qt][3]));
            float a1 = fmaxf(fmaxf(S[1][qt][0],S[1][qt][1]), fmaxf(S[1][qt][2],S[1][qt][3]));
            float a2 = fmaxf(fmaxf(S[2][qt][0],S[2][qt][1]), fmaxf(S[2][qt][2],S[2][qt][3]));
            float a3 = fmaxf(fmaxf(S[3][qt][0],S[3][qt][1]), fmaxf(S[3][qt][2],S[3][qt][3]));
            float p = fmaxf(fmaxf(a0,a1), fmaxf(a2,a3));
            p = fmaxf(p, __shfl_xor(p, 16));
            p = fmaxf(p, __shfl_xor(p, 32));
            pm[qt] = p;
        }
        bool grow = (pm[0] > m[0]+8.0f) | (pm[1] > m[1]+8.0f) |
                    (pm[2] > m[2]+8.0f) | (pm[3] > m[3]+8.0f);
        if (__any(grow)) {                      // defer-max (T13)
            float alpha[4];
            #pragma unroll
            for (int qt = 0; qt < 4; ++qt) {
                float mn = fmaxf(m[qt], pm[qt]);
                alpha[qt] = __builtin_amdgcn_exp2f(m[qt] - mn);
                lsum[qt] *= alpha[qt];
                m[qt] = mn;
            }
            #pragma unroll
            for (int qt = 0; qt < 4; ++qt)
                #pragma unroll
                for (int r = 0; r < 4; ++r) {
                    float a = __shfl(alpha[qt], hi*4 + r);   // alpha of q-row qt*16+hi*4+r
                    #pragma unroll
                    for (int dt = 0; dt < 4; ++dt) O[qt][dt][r] *= a;
                }
        }
        // P = exp2(S - m), pack to per-wave plds [q][k]
        #pragma unroll
        for (int qt = 0; qt < 4; ++qt) {
            float ps = 0.f;
            #pragma unroll
            for (int kt = 0; kt < 4; ++kt) {
                float p0 = __builtin_amdgcn_exp2f(S[kt][qt][0] - m[qt]);
                float p1 = __builtin_amdgcn_exp2f(S[kt][qt][1] - m[qt]);
                float p2 = __builtin_amdgcn_exp2f(S[kt][qt][2] - m[qt]);
                float p3 = __builtin_amdgcn_exp2f(S[kt][qt][3] - m[qt]);
                ps += (p0 + p1) + (p2 + p3);
                unsigned c01, c23;
                asm("v_cvt_pk_bf16_f32 %0, %1, %2" : "=v"(c01) : "v"(p0), "v"(p1));
                asm("v_cvt_pk_bf16_f32 %0, %1, %2" : "=v"(c23) : "v"(p2), "v"(p3));
                *(uint2*)&pl[(qt*16 + lo)*80 + kt*16 + hi*4] = make_uint2(c01, c23);
            }
            lsum[qt] += ps;
        }
        // PV: O[q][d] += P . V  (P as A-frag from plds; V from regs)
        __builtin_amdgcn_s_setprio(1);
        #pragma unroll
        for (int qt = 0; qt < 4; ++qt)
            #pragma unroll
            for (int kk = 0; kk < 2; ++kk) {
                s8v pa = *(const s8v*)&pl[(qt*16 + lo)*80 + kk*32 + hi*8];
                #pragma unroll
                for (int dt = 0; dt < 4; ++dt)
                    O[qt][dt] = __builtin_amdgcn_mfma_f32_16x16x32_bf16(pa, vf[kk][dt], O[qt][dt], 0, 0, 0);
            }
        __builtin_amdgcn_s_setprio(0);
    }

    // finish per-wave row-sums (reduce over hi groups)
    #pragma unroll
    for (int qt = 0; qt < 4; ++qt) {
        lsum[qt] += __shfl_xor(lsum[qt], 16);
        lsum[qt] += __shfl_xor(lsum[qt], 32);
    }

    __syncthreads();    // all waves done with plds (Ob overlaps it)

    if (hi == 0) {
        #pragma unroll
        for (int qt = 0; qt < 4; ++qt) {
            mb[w*64 + qt*16 + lo] = m[qt];
            lb[w*64 + qt*16 + lo] = lsum[qt];
        }
    }
    #pragma unroll
    for (int qt = 0; qt < 4; ++qt)
        #pragma unroll
        for (int dt = 0; dt < 4; ++dt)
            #pragma unroll
            for (int r = 0; r < 4; ++r)
                Ob[w*4224 + (qt*16 + hi*4 + r)*66 + dt*16 + lo] = O[qt][dt][r];
    __syncthreads();

    // merge: lane q = l handles all 64 q-rows' d-slice [w*16, w*16+16)
    {
        int q = l;
        float mw0 = mb[q], mw1 = mb[64+q], mw2 = mb[128+q], mw3 = mb[192+q];
        float ms = fmaxf(fmaxf(mw0,mw1), fmaxf(mw2,mw3));
        float c0 = __builtin_amdgcn_exp2f(mw0 - ms);
        float c1 = __builtin_amdgcn_exp2f(mw1 - ms);
        float c2 = __builtin_amdgcn_exp2f(mw2 - ms);
        float c3 = __builtin_amdgcn_exp2f(mw3 - ms);
        float ls = lb[q]*c0 + lb[64+q]*c1 + lb[128+q]*c2 + lb[192+q]*c3;
        float inv = 1.0f / ls;
        float* orow = out + ((size_t)h*LL + r0 + q)*DD + w*16;
        #pragma unroll
        for (int i4 = 0; i4 < 4; ++i4) {
            float4 o;
            #pragma unroll
            for (int e = 0; e < 4; ++e) {
                int d = w*16 + i4*4 + e;
                float acc = Ob[q*66 + d]*c0 + Ob[4224 + q*66 + d]*c1
                          + Ob[8448 + q*66 + d]*c2 + Ob[12672 + q*66 + d]*c3;
                ((float*)&o)[e] = acc * inv;
            }
            *(float4*)(orow + i4*4) = o;
        }
    }
}

extern "C" void kernel_launch(void* const* d_in, const int* in_sizes, int n_in,
                              void* d_out, int out_size, void* d_ws, size_t ws_size,
                              hipStream_t stream) {
    const float* q     = (const float*)d_in[0];
    const float* k     = (const float*)d_in[1];
    const float* v     = (const float*)d_in[2];
    const float* simth = (const float*)d_in[3];
    const float* cdfth = (const float*)d_in[4];
    float* out = (float*)d_out;

    float* ws    = (float*)d_ws;
    float* kpart = ws;                       // 16*8*64
    float* qm    = kpart + HH*8*64;          // 16*16*64
    float* km    = qm + HH*NQ*DD;            // 16*32*64
    int*   compq = (int*)(km + HH*NK*DD);    // 256
    int*   compk = compq + HH*NQ;            // 512
    unsigned* bmb = (unsigned*)(compk + HH*NK);  // 256
    size_t off = (size_t)((char*)(bmb + HH*NQ) - (char*)d_ws);
    off = (off + 15) & ~(size_t)15;
    ushort* qbuf = (ushort*)((char*)d_ws + off);
    ushort* kbuf = qbuf + (size_t)HH*LL*DD;
    ushort* vTb  = kbuf + (size_t)HH*LL*DD;

    kmean1_kernel<<<dim3(8, HH), 256, 0, stream>>>(k, kpart);
    stats_kernel<<<dim3(NQ + NK, HH), 128, 0, stream>>>(q, k, v, kpart, simth,
                                                        qm, km, compq, compk,
                                                        qbuf, kbuf, vTb);
    bmask_kernel<<<dim3(NQ, HH), NK, 0, stream>>>(qm, km, compq, compk, cdfth, bmb);
    attn_kernel<<<dim3(NQ*2, HH), 256, 0, stream>>>(qbuf, kbuf, vTb, bmb, out);
}